// Round 13
// baseline (1080.445 us; speedup 1.0000x reference)
//
#include <hip/hip_runtime.h>
#include <hip/hip_cooperative_groups.h>
#include <hip/hip_bf16.h>
#include <hip/hip_fp16.h>

#define D 64
#define K3E 4096
#define ECAP 6144   // slots per 256-node bucket (mean fill 4082, sigma 64 -> 32 sigma headroom)

// Edge word packing (requires N <= 65536, V <= 128 — true for this problem):
//   bits [0:15]  = src node
//   bits [16:22] = x[src]   (vocab id)
//   bits [23:30] = dst & 255 (node index within its 256-node bucket)
//
// Padded-bucket CSR: bucket b owns ebuf/col slots [b*ECAP, b*ECAP + fill_b).
// LESSONS (measured):
//  R6/R12: coupling gather with GEMM in one block (serial node loops + barrier)
//      is latency-death: R6 141us/kernel @25% occ; R12 48us/kernel @30% occ.
//      Gathers need 50k independent waves, 1 node/wave, no coupling.
//  R2: guarded (skipped) loads lose to clamped loads — MLP beats issue-waste.
//  R1: each removed serial dispatch ~= -6.7 us (launch gap). 10 dispatches
//      => ~60 us of gaps. R13: keep proven kernel shapes, replace 6 dispatch
//      boundaries with grid.sync() in ONE cooperative kernel (guide-blessed).

// ===== fused front-end: blocks [0,NG) compute embW = emb @ Wgcn (fp32);
//       blocks [NG,..) scatter edges into padded bucket regions. =====

__global__ __launch_bounds__(256) void embw_scatter_kernel(
    const float* __restrict__ emb, int nrows,
    const float* __restrict__ W1, float* __restrict__ embW, int NG,
    const int* __restrict__ src, const int* __restrict__ dst,
    const int* __restrict__ x,
    int* __restrict__ bucketFill, int* __restrict__ ebuf, int E)
{
    __shared__ union SM {
        struct { float At[64][68]; float Ws1[64][64]; } g;
        struct { int uu[K3E]; unsigned char bb[K3E]; int hist[256]; int resBase[256]; } s;
    } sm;
    int t = threadIdx.x;

    if ((int)blockIdx.x >= NG) {
        // ---- scatter half: one 4096-edge tile per block ----
        int bid = blockIdx.x - NG;
        int* uu = sm.s.uu;
        unsigned char* bb = sm.s.bb;
        int* hist = sm.s.hist;
        int* resBase = sm.s.resBase;
        hist[t] = 0;
        __syncthreads();
        int e0 = bid * K3E;
        int cnt = E - e0; if (cnt > K3E) cnt = K3E;
        for (int i = t; i < cnt; i += 256) {
            int e = e0 + i;
            int s = src[e];
            int d = dst[e];
            int xs = x[s];
            uu[i] = s | (xs << 16) | ((d & 255) << 23);
            int b = d >> 8;
            bb[i] = (unsigned char)b;
            atomicAdd(&hist[b], 1);
        }
        __syncthreads();
        int c = hist[t];
        if (c) resBase[t] = t * ECAP + atomicAdd(&bucketFill[t], c);
        __syncthreads();
        hist[t] = 0;
        __syncthreads();
        for (int i = t; i < cnt; i += 256) {
            int b = bb[i];
            int r = atomicAdd(&hist[b], 1);
            int idx = resBase[b] + r;
            if (idx < (b + 1) * ECAP) ebuf[idx] = uu[i];   // overflow guard (never hit at 32 sigma)
        }
        return;
    }

    // ---- embW GEMM half (fp32, V rows) ----
    {
        const float4* w1v = (const float4*)W1;
        float4* s1 = (float4*)&sm.g.Ws1[0][0];
        for (int i = t; i < 1024; i += 256) s1[i] = w1v[i];
    }
    int r0 = blockIdx.x * 64;
    for (int i = t; i < 1024; i += 256) {
        int r = i >> 4, c4 = i & 15;
        int gr = r0 + r; if (gr >= nrows) gr = nrows - 1;
        float4 v = ((const float4*)(emb + (size_t)gr * D))[c4];
        float* dp = &sm.g.At[r][c4 * 4];
        dp[0] = v.x; dp[1] = v.y; dp[2] = v.z; dp[3] = v.w;
    }
    __syncthreads();

    int cg = t & 15;
    int rg = t >> 4;
    float acc1[4][4] = {{0.f}};

    for (int k0 = 0; k0 < 64; k0 += 4) {
        float4 a[4], w1[4];
#pragma unroll
        for (int i = 0; i < 4; ++i) a[i] = *(const float4*)&sm.g.At[4 * rg + i][k0];
#pragma unroll
        for (int j = 0; j < 4; ++j) w1[j] = *(const float4*)&sm.g.Ws1[k0 + j][cg * 4];
#pragma unroll
        for (int i = 0; i < 4; ++i) {
            float av[4] = {a[i].x, a[i].y, a[i].z, a[i].w};
#pragma unroll
            for (int kk = 0; kk < 4; ++kk) {
                acc1[i][0] += av[kk] * w1[kk].x;
                acc1[i][1] += av[kk] * w1[kk].y;
                acc1[i][2] += av[kk] * w1[kk].z;
                acc1[i][3] += av[kk] * w1[kk].w;
            }
        }
    }
#pragma unroll
    for (int i = 0; i < 4; ++i) {
        int gr = r0 + 4 * rg + i;
        if (gr < nrows) {
            float4 o;
            o.x = acc1[i][0]; o.y = acc1[i][1]; o.z = acc1[i][2]; o.w = acc1[i][3];
            ((float4*)(embW + (size_t)gr * D))[cg] = o;
        }
    }
}

// ===== per-bucket exact CSR build (LDS 27 KB) =====

__global__ __launch_bounds__(1024) void csr_build_kernel(
    const int* __restrict__ ebuf, const int* __restrict__ bucketFill,
    int* __restrict__ rowbeg, int* __restrict__ rowend, int* __restrict__ col,
    int N)
{
    __shared__ int eLds[ECAP];       // 24 KB
    __shared__ int hist[256];        // 1 KB
    __shared__ int sc[256];          // 1 KB
    int b = blockIdx.x, t = threadIdx.x;
    int base = b * ECAP;
    int m = bucketFill[b]; if (m > ECAP) m = ECAP;

    if (t < 256) hist[t] = 0;
    __syncthreads();

    for (int i = t; i < m; i += 1024) {
        int u = ebuf[base + i];
        eLds[i] = u;
        atomicAdd(&hist[(u >> 23) & 255], 1);
    }
    __syncthreads();

    int v = (t < 256) ? hist[t] : 0;
    if (t < 256) sc[t] = v;
    __syncthreads();
    for (int off = 1; off < 256; off <<= 1) {
        int w = (t >= off && t < 256) ? sc[t - off] : 0;
        __syncthreads();
        if (t < 256) sc[t] += w;
        __syncthreads();
    }
    if (t < 256) {
        int excl = sc[t] - v;
        int node = (b << 8) + t;
        if (node < N) {
            rowbeg[node] = base + excl;
            rowend[node] = base + sc[t];
        }
        hist[t] = excl;   // running local cursor
    }
    __syncthreads();

    for (int i = t; i < m; i += 1024) {
        int u = eLds[i];
        int dl = (u >> 23) & 255;
        int r = atomicAdd(&hist[dl], 1);
        col[base + r] = u;
    }
}

// ===== cooperative middle: gather -> gemm1 -> sage_agg -> gemm2 -> gin_agg
//       -> gemm3 -> pool, with grid.sync() between phases.
// Each phase keeps its proven R7/R9 shape (1 node/wave aggs, gemm64h-pattern
// tiled GEMM with At in LDS + weights from global (L1-resident), 4-wave pool).
// 256 threads/block, 8 blocks/CU (LDS 17.4 KB, launch_bounds(256,8)).

__global__ __launch_bounds__(256, 8) void coop_mid_kernel(
    const int* __restrict__ rowbeg, const int* __restrict__ rowend,
    const int* __restrict__ col,
    const float* __restrict__ embW,
    const float* __restrict__ Wsl, const float* __restrict__ Wsr,
    const float* __restrict__ Wg1, const float* __restrict__ bg1,
    const float* __restrict__ Wg2, const float* __restrict__ bg2,
    const int* __restrict__ batch,
    const float* __restrict__ Wp1, const float* __restrict__ Wp2,
    const float* __restrict__ Wp3,
    __half* __restrict__ h1, __half* __restrict__ Ah, __half* __restrict__ Bm,
    __half* __restrict__ h2, __half* __restrict__ Ch, __half* __restrict__ h3,
    float* __restrict__ out, int N, int G)
{
    cooperative_groups::grid_group gg = cooperative_groups::this_grid();
    __shared__ union {
        float At[64][68];      // 17.4 KB (GEMM phases)
        float pr[3][4][64];    // 3 KB    (pool phase)
    } sm;
    int t = threadIdx.x;
    int bid = blockIdx.x;
    int nblk = gridDim.x;
    int w = t >> 6, lane = t & 63;
    int grp = lane >> 4, li = lane & 15;

    // ---- phase 1: GCN gather -> h1 (1 node/wave, clamped 32-edge unroll) ----
    for (int v = bid * 4 + w; v < N; v += nblk * 4) {
        int beg = rowbeg[v], end = rowend[v];
        float a0 = 0.f, a1 = 0.f, a2 = 0.f, a3 = 0.f;
        for (int e0 = beg; e0 < end; e0 += 32) {
#pragma unroll
            for (int j = 0; j < 8; ++j) {
                int e = e0 + 4 * j + grp;
                float m = (e < end) ? 1.f : 0.f;
                int ec = (e < end) ? e : (end - 1);
                int xu = (col[ec] >> 16) & 0x7F;
                float4 f = *((const float4*)(embW + (size_t)xu * D) + li);
                a0 += m * f.x; a1 += m * f.y; a2 += m * f.z; a3 += m * f.w;
            }
        }
        a0 += __shfl_xor(a0, 16); a0 += __shfl_xor(a0, 32);
        a1 += __shfl_xor(a1, 16); a1 += __shfl_xor(a1, 32);
        a2 += __shfl_xor(a2, 16); a2 += __shfl_xor(a2, 32);
        a3 += __shfl_xor(a3, 16); a3 += __shfl_xor(a3, 32);
        if (grp == 0) {
            float2 oh;
            *(__half2*)&oh.x = __floats2half2_rn(fmaxf(a0, 0.f), fmaxf(a1, 0.f));
            *(__half2*)&oh.y = __floats2half2_rn(fmaxf(a2, 0.f), fmaxf(a3, 0.f));
            ((float2*)(h1 + (size_t)v * D))[li] = oh;
        }
    }
    gg.sync();

    // ---- phase 2: Ah = h1@Wsl ; Bm = h1@Wsr (one At stage, two acc passes) ----
    {
        int cg = t & 15, rg = t >> 4;
        for (int tile = bid; tile * 64 < N; tile += nblk) {
            int r0 = tile * 64;
            __syncthreads();
            for (int i = t; i < 512; i += 256) {
                int r = i >> 3, c8 = i & 7;
                int gr = r0 + r; if (gr >= N) gr = N - 1;
                float4 hv = ((const float4*)(h1 + (size_t)gr * D))[c8];
                const __half2* hp = (const __half2*)&hv;
                float* dp = &sm.At[r][c8 * 8];
                float2 f;
                f = __half22float2(hp[0]); dp[0] = f.x; dp[1] = f.y;
                f = __half22float2(hp[1]); dp[2] = f.x; dp[3] = f.y;
                f = __half22float2(hp[2]); dp[4] = f.x; dp[5] = f.y;
                f = __half22float2(hp[3]); dp[6] = f.x; dp[7] = f.y;
            }
            __syncthreads();
            // pass A: Wsl -> Ah
            {
                float acc[4][4] = {{0.f}};
                for (int k0 = 0; k0 < 64; k0 += 4) {
                    float4 a[4], w1[4];
#pragma unroll
                    for (int i = 0; i < 4; ++i) a[i] = *(const float4*)&sm.At[4 * rg + i][k0];
#pragma unroll
                    for (int j = 0; j < 4; ++j)
                        w1[j] = *(const float4*)(Wsl + (size_t)(k0 + j) * 64 + cg * 4);
#pragma unroll
                    for (int i = 0; i < 4; ++i) {
                        float av[4] = {a[i].x, a[i].y, a[i].z, a[i].w};
#pragma unroll
                        for (int kk = 0; kk < 4; ++kk) {
                            acc[i][0] += av[kk] * w1[kk].x;
                            acc[i][1] += av[kk] * w1[kk].y;
                            acc[i][2] += av[kk] * w1[kk].z;
                            acc[i][3] += av[kk] * w1[kk].w;
                        }
                    }
                }
#pragma unroll
                for (int i = 0; i < 4; ++i) {
                    int gr = r0 + 4 * rg + i;
                    if (gr < N) {
                        float2 o;
                        *(__half2*)&o.x = __floats2half2_rn(acc[i][0], acc[i][1]);
                        *(__half2*)&o.y = __floats2half2_rn(acc[i][2], acc[i][3]);
                        ((float2*)(Ah + (size_t)gr * D))[cg] = o;
                    }
                }
            }
            // pass B: Wsr -> Bm (reuse At)
            {
                float acc[4][4] = {{0.f}};
                for (int k0 = 0; k0 < 64; k0 += 4) {
                    float4 a[4], w1[4];
#pragma unroll
                    for (int i = 0; i < 4; ++i) a[i] = *(const float4*)&sm.At[4 * rg + i][k0];
#pragma unroll
                    for (int j = 0; j < 4; ++j)
                        w1[j] = *(const float4*)(Wsr + (size_t)(k0 + j) * 64 + cg * 4);
#pragma unroll
                    for (int i = 0; i < 4; ++i) {
                        float av[4] = {a[i].x, a[i].y, a[i].z, a[i].w};
#pragma unroll
                        for (int kk = 0; kk < 4; ++kk) {
                            acc[i][0] += av[kk] * w1[kk].x;
                            acc[i][1] += av[kk] * w1[kk].y;
                            acc[i][2] += av[kk] * w1[kk].z;
                            acc[i][3] += av[kk] * w1[kk].w;
                        }
                    }
                }
#pragma unroll
                for (int i = 0; i < 4; ++i) {
                    int gr = r0 + 4 * rg + i;
                    if (gr < N) {
                        float2 o;
                        *(__half2*)&o.x = __floats2half2_rn(acc[i][0], acc[i][1]);
                        *(__half2*)&o.y = __floats2half2_rn(acc[i][2], acc[i][3]);
                        ((float2*)(Bm + (size_t)gr * D))[cg] = o;
                    }
                }
            }
        }
    }
    gg.sync();

    // ---- phase 3: SAGE agg: h2 = relu(agg(Ah)/deg + Bm) ----
    for (int v = bid * 4 + w; v < N; v += nblk * 4) {
        int beg = rowbeg[v], end = rowend[v];
        float a0 = 0.f, a1 = 0.f, a2 = 0.f, a3 = 0.f;
        for (int e0 = beg; e0 < end; e0 += 32) {
#pragma unroll
            for (int j = 0; j < 8; ++j) {
                int e = e0 + 4 * j + grp;
                float m = (e < end) ? 1.f : 0.f;
                int ec = (e < end) ? e : (end - 1);
                int u = col[ec] & 0xFFFF;
                float2 r = *((const float2*)(Ah + (size_t)u * D) + li);
                float2 f01 = __half22float2(*(const __half2*)&r.x);
                float2 f23 = __half22float2(*(const __half2*)&r.y);
                a0 += m * f01.x; a1 += m * f01.y; a2 += m * f23.x; a3 += m * f23.y;
            }
        }
        a0 += __shfl_xor(a0, 16); a0 += __shfl_xor(a0, 32);
        a1 += __shfl_xor(a1, 16); a1 += __shfl_xor(a1, 32);
        a2 += __shfl_xor(a2, 16); a2 += __shfl_xor(a2, 32);
        a3 += __shfl_xor(a3, 16); a3 += __shfl_xor(a3, 32);
        if (grp == 0) {
            float inv = 1.f / fmaxf((float)(end - beg), 1.f);
            float2 br = *((const float2*)(Bm + (size_t)v * D) + li);
            float2 b01 = __half22float2(*(const __half2*)&br.x);
            float2 b23 = __half22float2(*(const __half2*)&br.y);
            float2 oh;
            *(__half2*)&oh.x = __floats2half2_rn(fmaxf(a0 * inv + b01.x, 0.f),
                                                 fmaxf(a1 * inv + b01.y, 0.f));
            *(__half2*)&oh.y = __floats2half2_rn(fmaxf(a2 * inv + b23.x, 0.f),
                                                 fmaxf(a3 * inv + b23.y, 0.f));
            ((float2*)(h2 + (size_t)v * D))[li] = oh;
        }
    }
    gg.sync();

    // ---- phase 4: Ch = h2@Wg1 ----
    {
        int cg = t & 15, rg = t >> 4;
        for (int tile = bid; tile * 64 < N; tile += nblk) {
            int r0 = tile * 64;
            __syncthreads();
            for (int i = t; i < 512; i += 256) {
                int r = i >> 3, c8 = i & 7;
                int gr = r0 + r; if (gr >= N) gr = N - 1;
                float4 hv = ((const float4*)(h2 + (size_t)gr * D))[c8];
                const __half2* hp = (const __half2*)&hv;
                float* dp = &sm.At[r][c8 * 8];
                float2 f;
                f = __half22float2(hp[0]); dp[0] = f.x; dp[1] = f.y;
                f = __half22float2(hp[1]); dp[2] = f.x; dp[3] = f.y;
                f = __half22float2(hp[2]); dp[4] = f.x; dp[5] = f.y;
                f = __half22float2(hp[3]); dp[6] = f.x; dp[7] = f.y;
            }
            __syncthreads();
            float acc[4][4] = {{0.f}};
            for (int k0 = 0; k0 < 64; k0 += 4) {
                float4 a[4], w1[4];
#pragma unroll
                for (int i = 0; i < 4; ++i) a[i] = *(const float4*)&sm.At[4 * rg + i][k0];
#pragma unroll
                for (int j = 0; j < 4; ++j)
                    w1[j] = *(const float4*)(Wg1 + (size_t)(k0 + j) * 64 + cg * 4);
#pragma unroll
                for (int i = 0; i < 4; ++i) {
                    float av[4] = {a[i].x, a[i].y, a[i].z, a[i].w};
#pragma unroll
                    for (int kk = 0; kk < 4; ++kk) {
                        acc[i][0] += av[kk] * w1[kk].x;
                        acc[i][1] += av[kk] * w1[kk].y;
                        acc[i][2] += av[kk] * w1[kk].z;
                        acc[i][3] += av[kk] * w1[kk].w;
                    }
                }
            }
#pragma unroll
            for (int i = 0; i < 4; ++i) {
                int gr = r0 + 4 * rg + i;
                if (gr < N) {
                    float2 o;
                    *(__half2*)&o.x = __floats2half2_rn(acc[i][0], acc[i][1]);
                    *(__half2*)&o.y = __floats2half2_rn(acc[i][2], acc[i][3]);
                    ((float2*)(Ch + (size_t)gr * D))[cg] = o;
                }
            }
        }
    }
    gg.sync();

    // ---- phase 5: GIN agg: Bm(reused as t) = relu(Ch[v] + agg(Ch) + bg1) ----
    for (int v = bid * 4 + w; v < N; v += nblk * 4) {
        int beg = rowbeg[v], end = rowend[v];
        float a0 = 0.f, a1 = 0.f, a2 = 0.f, a3 = 0.f;
        for (int e0 = beg; e0 < end; e0 += 32) {
#pragma unroll
            for (int j = 0; j < 8; ++j) {
                int e = e0 + 4 * j + grp;
                float m = (e < end) ? 1.f : 0.f;
                int ec = (e < end) ? e : (end - 1);
                int u = col[ec] & 0xFFFF;
                float2 r = *((const float2*)(Ch + (size_t)u * D) + li);
                float2 f01 = __half22float2(*(const __half2*)&r.x);
                float2 f23 = __half22float2(*(const __half2*)&r.y);
                a0 += m * f01.x; a1 += m * f01.y; a2 += m * f23.x; a3 += m * f23.y;
            }
        }
        a0 += __shfl_xor(a0, 16); a0 += __shfl_xor(a0, 32);
        a1 += __shfl_xor(a1, 16); a1 += __shfl_xor(a1, 32);
        a2 += __shfl_xor(a2, 16); a2 += __shfl_xor(a2, 32);
        a3 += __shfl_xor(a3, 16); a3 += __shfl_xor(a3, 32);
        if (grp == 0) {
            float2 rs = *((const float2*)(Ch + (size_t)v * D) + li);   // self term
            float2 s01 = __half22float2(*(const __half2*)&rs.x);
            float2 s23 = __half22float2(*(const __half2*)&rs.y);
            float4 bb = ((const float4*)bg1)[li];
            float2 oh;
            *(__half2*)&oh.x = __floats2half2_rn(fmaxf(s01.x + a0 + bb.x, 0.f),
                                                 fmaxf(s01.y + a1 + bb.y, 0.f));
            *(__half2*)&oh.y = __floats2half2_rn(fmaxf(s23.x + a2 + bb.z, 0.f),
                                                 fmaxf(s23.y + a3 + bb.w, 0.f));
            ((float2*)(Bm + (size_t)v * D))[li] = oh;
        }
    }
    gg.sync();

    // ---- phase 6: h3 = relu(Bm@Wg2 + bg2) ----
    {
        int cg = t & 15, rg = t >> 4;
        for (int tile = bid; tile * 64 < N; tile += nblk) {
            int r0 = tile * 64;
            __syncthreads();
            for (int i = t; i < 512; i += 256) {
                int r = i >> 3, c8 = i & 7;
                int gr = r0 + r; if (gr >= N) gr = N - 1;
                float4 hv = ((const float4*)(Bm + (size_t)gr * D))[c8];
                const __half2* hp = (const __half2*)&hv;
                float* dp = &sm.At[r][c8 * 8];
                float2 f;
                f = __half22float2(hp[0]); dp[0] = f.x; dp[1] = f.y;
                f = __half22float2(hp[1]); dp[2] = f.x; dp[3] = f.y;
                f = __half22float2(hp[2]); dp[4] = f.x; dp[5] = f.y;
                f = __half22float2(hp[3]); dp[6] = f.x; dp[7] = f.y;
            }
            __syncthreads();
            float acc[4][4] = {{0.f}};
            for (int k0 = 0; k0 < 64; k0 += 4) {
                float4 a[4], w1[4];
#pragma unroll
                for (int i = 0; i < 4; ++i) a[i] = *(const float4*)&sm.At[4 * rg + i][k0];
#pragma unroll
                for (int j = 0; j < 4; ++j)
                    w1[j] = *(const float4*)(Wg2 + (size_t)(k0 + j) * 64 + cg * 4);
#pragma unroll
                for (int i = 0; i < 4; ++i) {
                    float av[4] = {a[i].x, a[i].y, a[i].z, a[i].w};
#pragma unroll
                    for (int kk = 0; kk < 4; ++kk) {
                        acc[i][0] += av[kk] * w1[kk].x;
                        acc[i][1] += av[kk] * w1[kk].y;
                        acc[i][2] += av[kk] * w1[kk].z;
                        acc[i][3] += av[kk] * w1[kk].w;
                    }
                }
            }
            float4 bv = ((const float4*)bg2)[cg];
#pragma unroll
            for (int i = 0; i < 4; ++i) {
                int gr = r0 + 4 * rg + i;
                if (gr < N) {
                    float2 o;
                    *(__half2*)&o.x = __floats2half2_rn(fmaxf(acc[i][0] + bv.x, 0.f),
                                                        fmaxf(acc[i][1] + bv.y, 0.f));
                    *(__half2*)&o.y = __floats2half2_rn(fmaxf(acc[i][2] + bv.z, 0.f),
                                                        fmaxf(acc[i][3] + bv.w, 0.f));
                    ((float2*)(h3 + (size_t)gr * D))[cg] = o;
                }
            }
        }
    }
    gg.sync();

    // ---- phase 7: pooling (4 waves/graph, grid-stride over graphs) ----
    {
        int half = lane >> 5, lc = lane & 31;
        for (int g = bid; g < G; g += nblk) {
            int lo = 0, hi = N;
            while (lo < hi) { int mid = (lo + hi) >> 1; if (batch[mid] < g) lo = mid + 1; else hi = mid; }
            int beg = lo;
            hi = N;
            while (lo < hi) { int mid = (lo + hi) >> 1; if (batch[mid] < g + 1) lo = mid + 1; else hi = mid; }
            int end = lo;

            float s1x = 0.f, s1y = 0.f, s2x = 0.f, s2y = 0.f, s3x = 0.f, s3y = 0.f;
            for (int v = beg + 2 * w + half; v < end; v += 8) {
                size_t ro = (size_t)v * D;
                float2 f1 = __half22float2(((const __half2*)(h1 + ro))[lc]);
                float2 f2 = __half22float2(((const __half2*)(h2 + ro))[lc]);
                float2 f3 = __half22float2(((const __half2*)(h3 + ro))[lc]);
                s1x += f1.x; s1y += f1.y;
                s2x += f2.x; s2y += f2.y;
                s3x += f3.x; s3y += f3.y;
            }
            s1x += __shfl_xor(s1x, 32); s1y += __shfl_xor(s1y, 32);
            s2x += __shfl_xor(s2x, 32); s2y += __shfl_xor(s2y, 32);
            s3x += __shfl_xor(s3x, 32); s3y += __shfl_xor(s3y, 32);
            if (half == 0) {
                ((float2*)sm.pr[0][w])[lc] = make_float2(s1x, s1y);
                ((float2*)sm.pr[1][w])[lc] = make_float2(s2x, s2y);
                ((float2*)sm.pr[2][w])[lc] = make_float2(s3x, s3y);
            }
            __syncthreads();
            if (w < 2) {
                sm.pr[0][w][lane] += sm.pr[0][w + 2][lane];
                sm.pr[1][w][lane] += sm.pr[1][w + 2][lane];
                sm.pr[2][w][lane] += sm.pr[2][w + 2][lane];
            }
            __syncthreads();
            if (w == 0) {
                float inv = 1.f / fmaxf((float)(end - beg), 1.f);
                float p1 = (sm.pr[0][0][lane] + sm.pr[0][1][lane]) * inv;
                float p2 = (sm.pr[1][0][lane] + sm.pr[1][1][lane]) * inv;
                float p3 = (sm.pr[2][0][lane] + sm.pr[2][1][lane]) * inv;
                float acc = 0.f;
#pragma unroll
                for (int k = 0; k < D; ++k) {
                    acc += __shfl(p1, k) * Wp1[k * D + lane]
                         + __shfl(p2, k) * Wp2[k * D + lane]
                         + __shfl(p3, k) * Wp3[k * D + lane];
                }
                out[(size_t)g * D + lane] = fmaxf(acc, 0.f);
            }
            __syncthreads();
        }
    }
}

// ================= launch =================

static inline size_t align256(size_t x) { return (x + 255) & ~(size_t)255; }

extern "C" void kernel_launch(void* const* d_in, const int* in_sizes, int n_in,
                              void* d_out, int out_size, void* d_ws, size_t ws_size,
                              hipStream_t stream) {
    const int* x      = (const int*)d_in[0];
    const int* ei     = (const int*)d_in[1];
    const int* batch  = (const int*)d_in[2];
    const float* emb  = (const float*)d_in[3];
    const float* Wgcn = (const float*)d_in[4];
    const float* Wsl  = (const float*)d_in[5];
    const float* Wsr  = (const float*)d_in[6];
    const float* Wg1  = (const float*)d_in[7];
    const float* bg1  = (const float*)d_in[8];
    const float* Wg2  = (const float*)d_in[9];
    const float* bg2  = (const float*)d_in[10];
    const float* Wp1  = (const float*)d_in[11];
    const float* Wp2  = (const float*)d_in[12];
    const float* Wp3  = (const float*)d_in[13];
    float* out = (float*)d_out;

    const int N = in_sizes[0];
    const int E = in_sizes[1] / 2;
    const int V = in_sizes[3] / D;
    const int G = out_size / D;
    const int* src = ei;
    const int* dst = ei + E;
    const int NBUCK = (N + 255) >> 8;

    // workspace layout
    char* base = (char*)d_ws;
    size_t off = 0;
    float* embW       = (float*)(base + off); off = align256(off + (size_t)V * D * 4);
    int* bucketFill   = (int*)(base + off);   off = align256(off + 256 * 4);
    int* rowbeg       = (int*)(base + off);   off = align256(off + (size_t)N * 4);
    int* rowend       = (int*)(base + off);   off = align256(off + (size_t)N * 4);
    int* ebuf         = (int*)(base + off);   off = align256(off + (size_t)NBUCK * ECAP * 4);
    int* col          = (int*)(base + off);   off = align256(off + (size_t)NBUCK * ECAP * 4);
    __half* h1        = (__half*)(base + off); off = align256(off + (size_t)N * D * 2);
    __half* h2        = (__half*)(base + off); off = align256(off + (size_t)N * D * 2);
    __half* h3        = (__half*)(base + off); off = align256(off + (size_t)N * D * 2);
    __half* Ah        = (__half*)(base + off); off = align256(off + (size_t)N * D * 2);
    __half* Bm        = (__half*)(base + off); off = align256(off + (size_t)N * D * 2);
    (void)ws_size;

    __half* Ch = Ah;  // reuse: Ah dead after phase 3; Ch written in phase 4

    hipMemsetAsync(bucketFill, 0, 256 * 4, stream);

    // fused: embW = emb @ Wgcn (blocks [0,NG)) + padded-bucket edge scatter (rest)
    const int NG = (V + 63) / 64;
    const int NTILE = (E + K3E - 1) / K3E;
    embw_scatter_kernel<<<NG + NTILE, 256, 0, stream>>>(emb, V, Wgcn, embW, NG,
                                                        src, dst, x, bucketFill, ebuf, E);

    // CSR build (per-bucket exact)
    csr_build_kernel<<<NBUCK, 1024, 0, stream>>>(ebuf, bucketFill, rowbeg, rowend, col, N);

    // cooperative middle: gather..gemm3..pool in ONE kernel (grid.sync phases)
    static int coopGrid = 0;
    if (coopGrid == 0) {
        int maxb = 0;
        hipError_t err = hipOccupancyMaxActiveBlocksPerMultiprocessor(
            &maxb, (const void*)coop_mid_kernel, 256, 0);
        int nCU = 256;
        hipDeviceProp_t prop;
        int dev = 0;
        if (hipGetDevice(&dev) == hipSuccess &&
            hipGetDeviceProperties(&prop, dev) == hipSuccess)
            nCU = prop.multiProcessorCount;
        if (err != hipSuccess || maxb <= 0) maxb = 4;   // conservative fallback
        coopGrid = maxb * nCU;
        if (coopGrid > 2048) coopGrid = 2048;
        if (coopGrid < 256) coopGrid = 256;
    }

    void* cargs[] = {
        (void*)&rowbeg, (void*)&rowend, (void*)&col, (void*)&embW,
        (void*)&Wsl, (void*)&Wsr, (void*)&Wg1, (void*)&bg1,
        (void*)&Wg2, (void*)&bg2, (void*)&batch,
        (void*)&Wp1, (void*)&Wp2, (void*)&Wp3,
        (void*)&h1, (void*)&Ah, (void*)&Bm, (void*)&h2, (void*)&Ch, (void*)&h3,
        (void*)&out, (void*)&N, (void*)&G
    };
    hipLaunchCooperativeKernel((const void*)coop_mid_kernel,
                               dim3(coopGrid), dim3(256), cargs, 0, stream);
}

// Round 14
// 233.208 us; speedup vs baseline: 4.6330x; 4.6330x over previous
//
#include <hip/hip_runtime.h>
#include <hip/hip_bf16.h>
#include <hip/hip_fp16.h>

#define D 64
#define K3E 4096
#define ECAP 6144   // slots per 256-node bucket (mean fill 4082, sigma 64 -> 32 sigma headroom)

// Edge word packing (requires N <= 65536, V <= 128 — true for this problem):
//   bits [0:15]  = src node
//   bits [16:22] = x[src]   (vocab id)
//   bits [23:30] = dst & 255 (node index within its 256-node bucket)
//
// Padded-bucket CSR: bucket b owns ebuf/col slots [b*ECAP, b*ECAP + fill_b).
// LESSONS (measured):
//  R6/R12/R13: ALL coupling of gather with downstream compute loses:
//    R6 per-node shuffle-GEMM 141us@25%occ; R12 block-fused 48us@30%occ;
//    R13 cooperative grid.sync = 1660us (VALUBusy 3%, barrier spin traffic).
//    The 10-dispatch serial pipeline IS the optimal known structure.
//  R2: guarded (skipped) loads lose to clamped loads — MLP beats issue-waste.
//  R14: aggs gather 16B/lane (float4) instead of 8B — halves gather issue
//    count per edge (G13 coalescing sweet spot). Math identical.

// ===== fused front-end: blocks [0,NG) compute embW = emb @ Wgcn (fp32);
//       blocks [NG,..) scatter edges into padded bucket regions. =====

__global__ __launch_bounds__(256) void embw_scatter_kernel(
    const float* __restrict__ emb, int nrows,
    const float* __restrict__ W1, float* __restrict__ embW, int NG,
    const int* __restrict__ src, const int* __restrict__ dst,
    const int* __restrict__ x,
    int* __restrict__ bucketFill, int* __restrict__ ebuf, int E)
{
    __shared__ union SM {
        struct { float At[64][68]; float Ws1[64][64]; } g;
        struct { int uu[K3E]; unsigned char bb[K3E]; int hist[256]; int resBase[256]; } s;
    } sm;
    int t = threadIdx.x;

    if ((int)blockIdx.x >= NG) {
        // ---- scatter half: one 4096-edge tile per block ----
        int bid = blockIdx.x - NG;
        int* uu = sm.s.uu;
        unsigned char* bb = sm.s.bb;
        int* hist = sm.s.hist;
        int* resBase = sm.s.resBase;
        hist[t] = 0;
        __syncthreads();
        int e0 = bid * K3E;
        int cnt = E - e0; if (cnt > K3E) cnt = K3E;
        for (int i = t; i < cnt; i += 256) {
            int e = e0 + i;
            int s = src[e];
            int d = dst[e];
            int xs = x[s];
            uu[i] = s | (xs << 16) | ((d & 255) << 23);
            int b = d >> 8;
            bb[i] = (unsigned char)b;
            atomicAdd(&hist[b], 1);
        }
        __syncthreads();
        int c = hist[t];
        if (c) resBase[t] = t * ECAP + atomicAdd(&bucketFill[t], c);
        __syncthreads();
        hist[t] = 0;
        __syncthreads();
        for (int i = t; i < cnt; i += 256) {
            int b = bb[i];
            int r = atomicAdd(&hist[b], 1);
            int idx = resBase[b] + r;
            if (idx < (b + 1) * ECAP) ebuf[idx] = uu[i];   // overflow guard (never hit at 32 sigma)
        }
        return;
    }

    // ---- embW GEMM half (fp32, V rows) ----
    {
        const float4* w1v = (const float4*)W1;
        float4* s1 = (float4*)&sm.g.Ws1[0][0];
        for (int i = t; i < 1024; i += 256) s1[i] = w1v[i];
    }
    int r0 = blockIdx.x * 64;
    for (int i = t; i < 1024; i += 256) {
        int r = i >> 4, c4 = i & 15;
        int gr = r0 + r; if (gr >= nrows) gr = nrows - 1;
        float4 v = ((const float4*)(emb + (size_t)gr * D))[c4];
        float* dp = &sm.g.At[r][c4 * 4];
        dp[0] = v.x; dp[1] = v.y; dp[2] = v.z; dp[3] = v.w;
    }
    __syncthreads();

    int cg = t & 15;
    int rg = t >> 4;
    float acc1[4][4] = {{0.f}};

    for (int k0 = 0; k0 < 64; k0 += 4) {
        float4 a[4], w1[4];
#pragma unroll
        for (int i = 0; i < 4; ++i) a[i] = *(const float4*)&sm.g.At[4 * rg + i][k0];
#pragma unroll
        for (int j = 0; j < 4; ++j) w1[j] = *(const float4*)&sm.g.Ws1[k0 + j][cg * 4];
#pragma unroll
        for (int i = 0; i < 4; ++i) {
            float av[4] = {a[i].x, a[i].y, a[i].z, a[i].w};
#pragma unroll
            for (int kk = 0; kk < 4; ++kk) {
                acc1[i][0] += av[kk] * w1[kk].x;
                acc1[i][1] += av[kk] * w1[kk].y;
                acc1[i][2] += av[kk] * w1[kk].z;
                acc1[i][3] += av[kk] * w1[kk].w;
            }
        }
    }
#pragma unroll
    for (int i = 0; i < 4; ++i) {
        int gr = r0 + 4 * rg + i;
        if (gr < nrows) {
            float4 o;
            o.x = acc1[i][0]; o.y = acc1[i][1]; o.z = acc1[i][2]; o.w = acc1[i][3];
            ((float4*)(embW + (size_t)gr * D))[cg] = o;
        }
    }
}

// ===== per-bucket exact CSR build (LDS 27 KB) =====

__global__ __launch_bounds__(1024) void csr_build_kernel(
    const int* __restrict__ ebuf, const int* __restrict__ bucketFill,
    int* __restrict__ rowbeg, int* __restrict__ rowend, int* __restrict__ col,
    int N)
{
    __shared__ int eLds[ECAP];       // 24 KB
    __shared__ int hist[256];        // 1 KB
    __shared__ int sc[256];          // 1 KB
    int b = blockIdx.x, t = threadIdx.x;
    int base = b * ECAP;
    int m = bucketFill[b]; if (m > ECAP) m = ECAP;

    if (t < 256) hist[t] = 0;
    __syncthreads();

    for (int i = t; i < m; i += 1024) {
        int u = ebuf[base + i];
        eLds[i] = u;
        atomicAdd(&hist[(u >> 23) & 255], 1);
    }
    __syncthreads();

    int v = (t < 256) ? hist[t] : 0;
    if (t < 256) sc[t] = v;
    __syncthreads();
    for (int off = 1; off < 256; off <<= 1) {
        int w = (t >= off && t < 256) ? sc[t - off] : 0;
        __syncthreads();
        if (t < 256) sc[t] += w;
        __syncthreads();
    }
    if (t < 256) {
        int excl = sc[t] - v;
        int node = (b << 8) + t;
        if (node < N) {
            rowbeg[node] = base + excl;
            rowend[node] = base + sc[t];
        }
        hist[t] = excl;   // running local cursor
    }
    __syncthreads();

    for (int i = t; i < m; i += 1024) {
        int u = eLds[i];
        int dl = (u >> 23) & 255;
        int r = atomicAdd(&hist[dl], 1);
        col[base + r] = u;
    }
}

// ===== GCN gather at full occupancy: h1[v] = relu(sum_nb embW[x[u]]) =====

__global__ __launch_bounds__(256) void gcn_gather_kernel(
    const int* __restrict__ rowbeg, const int* __restrict__ rowend,
    const int* __restrict__ col,
    const float* __restrict__ embW,
    __half* __restrict__ h1, int N)
{
    int tid = threadIdx.x;
    int lane = tid & 63;
    int grp = lane >> 4, li = lane & 15;
    int v = blockIdx.x * 4 + (tid >> 6);
    if (v >= N) return;
    int beg = rowbeg[v], end = rowend[v];
    float a0 = 0.f, a1 = 0.f, a2 = 0.f, a3 = 0.f;
    for (int e0 = beg; e0 < end; e0 += 32) {
#pragma unroll
        for (int j = 0; j < 8; ++j) {
            int e = e0 + 4 * j + grp;
            float m = (e < end) ? 1.f : 0.f;
            int ec = (e < end) ? e : (end - 1);
            int xu = (col[ec] >> 16) & 0x7F;
            float4 f = *((const float4*)(embW + (size_t)xu * D) + li);
            a0 += m * f.x; a1 += m * f.y; a2 += m * f.z; a3 += m * f.w;
        }
    }
    a0 += __shfl_xor(a0, 16); a0 += __shfl_xor(a0, 32);
    a1 += __shfl_xor(a1, 16); a1 += __shfl_xor(a1, 32);
    a2 += __shfl_xor(a2, 16); a2 += __shfl_xor(a2, 32);
    a3 += __shfl_xor(a3, 16); a3 += __shfl_xor(a3, 32);
    if (grp == 0) {
        float2 oh;
        *(__half2*)&oh.x = __floats2half2_rn(fmaxf(a0, 0.f), fmaxf(a1, 0.f));
        *(__half2*)&oh.y = __floats2half2_rn(fmaxf(a2, 0.f), fmaxf(a3, 0.f));
        ((float2*)(h1 + (size_t)v * D))[li] = oh;
    }
}

// ===== fp16-in / fp16-out GEMM (fp32 LDS + fp32 accumulate), optional dual output =====

__global__ __launch_bounds__(256) void gemm64h_kernel(
    const __half* __restrict__ in, int nrows,
    const float* __restrict__ W1, const float* __restrict__ W2,
    const float* __restrict__ bias, int do_relu,
    __half* __restrict__ out1, __half* __restrict__ out2)
{
    __shared__ float At[64][68];
    __shared__ float Ws1[64][64];
    __shared__ float Ws2[64][64];
    int tid = threadIdx.x;
    {
        const float4* w1v = (const float4*)W1;
        float4* s1 = (float4*)&Ws1[0][0];
        for (int i = tid; i < 1024; i += 256) s1[i] = w1v[i];
        if (W2) {
            const float4* w2v = (const float4*)W2;
            float4* s2 = (float4*)&Ws2[0][0];
            for (int i = tid; i < 1024; i += 256) s2[i] = w2v[i];
        }
    }
    int r0 = blockIdx.x * 64;
    for (int i = tid; i < 512; i += 256) {
        int r = i >> 3, c8 = i & 7;
        int gr = r0 + r; if (gr >= nrows) gr = nrows - 1;
        float4 hv = ((const float4*)(in + (size_t)gr * D))[c8];
        const __half2* hp = (const __half2*)&hv;
        float* dp = &At[r][c8 * 8];
        float2 f;
        f = __half22float2(hp[0]); dp[0] = f.x; dp[1] = f.y;
        f = __half22float2(hp[1]); dp[2] = f.x; dp[3] = f.y;
        f = __half22float2(hp[2]); dp[4] = f.x; dp[5] = f.y;
        f = __half22float2(hp[3]); dp[6] = f.x; dp[7] = f.y;
    }
    __syncthreads();

    int cg = tid & 15;
    int rg = tid >> 4;
    float acc1[4][4] = {{0.f}}, acc2[4][4] = {{0.f}};

    for (int k0 = 0; k0 < 64; k0 += 4) {
        float4 a[4], w1[4];
#pragma unroll
        for (int i = 0; i < 4; ++i) a[i] = *(const float4*)&At[4 * rg + i][k0];
#pragma unroll
        for (int j = 0; j < 4; ++j) w1[j] = *(const float4*)&Ws1[k0 + j][cg * 4];
#pragma unroll
        for (int i = 0; i < 4; ++i) {
            float av[4] = {a[i].x, a[i].y, a[i].z, a[i].w};
#pragma unroll
            for (int kk = 0; kk < 4; ++kk) {
                acc1[i][0] += av[kk] * w1[kk].x;
                acc1[i][1] += av[kk] * w1[kk].y;
                acc1[i][2] += av[kk] * w1[kk].z;
                acc1[i][3] += av[kk] * w1[kk].w;
            }
        }
        if (W2) {
            float4 w2[4];
#pragma unroll
            for (int j = 0; j < 4; ++j) w2[j] = *(const float4*)&Ws2[k0 + j][cg * 4];
#pragma unroll
            for (int i = 0; i < 4; ++i) {
                float av[4] = {a[i].x, a[i].y, a[i].z, a[i].w};
#pragma unroll
                for (int kk = 0; kk < 4; ++kk) {
                    acc2[i][0] += av[kk] * w2[kk].x;
                    acc2[i][1] += av[kk] * w2[kk].y;
                    acc2[i][2] += av[kk] * w2[kk].z;
                    acc2[i][3] += av[kk] * w2[kk].w;
                }
            }
        }
    }

    float4 bv = make_float4(0.f, 0.f, 0.f, 0.f);
    if (bias) bv = ((const float4*)bias)[cg];
#pragma unroll
    for (int i = 0; i < 4; ++i) {
        int gr = r0 + 4 * rg + i;
        if (gr < nrows) {
            float ox = acc1[i][0] + bv.x, oy = acc1[i][1] + bv.y;
            float oz = acc1[i][2] + bv.z, ow = acc1[i][3] + bv.w;
            if (do_relu) {
                ox = fmaxf(ox, 0.f); oy = fmaxf(oy, 0.f);
                oz = fmaxf(oz, 0.f); ow = fmaxf(ow, 0.f);
            }
            float2 oh;
            *(__half2*)&oh.x = __floats2half2_rn(ox, oy);
            *(__half2*)&oh.y = __floats2half2_rn(oz, ow);
            ((float2*)(out1 + (size_t)gr * D))[cg] = oh;
            if (out2) {
                float2 o2;
                *(__half2*)&o2.x = __floats2half2_rn(acc2[i][0], acc2[i][1]);
                *(__half2*)&o2.y = __floats2half2_rn(acc2[i][2], acc2[i][3]);
                ((float2*)(out2 + (size_t)gr * D))[cg] = o2;
            }
        }
    }
}

// ===== SAGE epilogue: h2 = relu( agg(A)/deg + B ) — float4 (16B/lane) gathers =====
// 8 lane-groups x 8 lanes; 32-edge clamped iter = 4 wide loads/lane (was 8 narrow).

__global__ __launch_bounds__(256) void sage_agg_kernel(const int* __restrict__ rowbeg,
                                                       const int* __restrict__ rowend,
                                                       const int* __restrict__ col,
                                                       const __half* __restrict__ A,
                                                       const __half* __restrict__ B,
                                                       __half* __restrict__ h2, int N) {
    int tid = threadIdx.x;
    int lane = tid & 63;
    int grp = lane >> 3, li = lane & 7;
    int v = blockIdx.x * 4 + (tid >> 6);
    if (v >= N) return;
    int beg = rowbeg[v], end = rowend[v];
    float a[8] = {0.f, 0.f, 0.f, 0.f, 0.f, 0.f, 0.f, 0.f};
    for (int e0 = beg; e0 < end; e0 += 32) {
#pragma unroll
        for (int j = 0; j < 4; ++j) {
            int e = e0 + 8 * j + grp;
            float m = (e < end) ? 1.f : 0.f;
            int ec = (e < end) ? e : (end - 1);
            int u = col[ec] & 0xFFFF;
            float4 r = *((const float4*)(A + (size_t)u * D) + li);
            const __half2* hp = (const __half2*)&r;
            float2 f0 = __half22float2(hp[0]);
            float2 f1 = __half22float2(hp[1]);
            float2 f2 = __half22float2(hp[2]);
            float2 f3 = __half22float2(hp[3]);
            a[0] += m * f0.x; a[1] += m * f0.y; a[2] += m * f1.x; a[3] += m * f1.y;
            a[4] += m * f2.x; a[5] += m * f2.y; a[6] += m * f3.x; a[7] += m * f3.y;
        }
    }
#pragma unroll
    for (int k = 0; k < 8; ++k) {
        a[k] += __shfl_xor(a[k], 8);
        a[k] += __shfl_xor(a[k], 16);
        a[k] += __shfl_xor(a[k], 32);
    }
    if (grp == 0) {
        float inv = 1.f / fmaxf((float)(end - beg), 1.f);
        float4 br = *((const float4*)(B + (size_t)v * D) + li);
        const __half2* bp = (const __half2*)&br;
        float2 b0 = __half22float2(bp[0]);
        float2 b1 = __half22float2(bp[1]);
        float2 b2 = __half22float2(bp[2]);
        float2 b3 = __half22float2(bp[3]);
        float4 o;
        ((__half2*)&o)[0] = __floats2half2_rn(fmaxf(a[0] * inv + b0.x, 0.f),
                                              fmaxf(a[1] * inv + b0.y, 0.f));
        ((__half2*)&o)[1] = __floats2half2_rn(fmaxf(a[2] * inv + b1.x, 0.f),
                                              fmaxf(a[3] * inv + b1.y, 0.f));
        ((__half2*)&o)[2] = __floats2half2_rn(fmaxf(a[4] * inv + b2.x, 0.f),
                                              fmaxf(a[5] * inv + b2.y, 0.f));
        ((__half2*)&o)[3] = __floats2half2_rn(fmaxf(a[6] * inv + b3.x, 0.f),
                                              fmaxf(a[7] * inv + b3.y, 0.f));
        ((float4*)(h2 + (size_t)v * D))[li] = o;
    }
}

// ===== GIN epilogue: t = relu( C + agg(C) + b1 ) — float4 (16B/lane) gathers =====

__global__ __launch_bounds__(256) void gin_agg_kernel(const int* __restrict__ rowbeg,
                                                      const int* __restrict__ rowend,
                                                      const int* __restrict__ col,
                                                      const __half* __restrict__ C,
                                                      const float* __restrict__ b1,
                                                      __half* __restrict__ t, int N) {
    int tid = threadIdx.x;
    int lane = tid & 63;
    int grp = lane >> 3, li = lane & 7;
    int v = blockIdx.x * 4 + (tid >> 6);
    if (v >= N) return;
    int beg = rowbeg[v], end = rowend[v];
    float a[8] = {0.f, 0.f, 0.f, 0.f, 0.f, 0.f, 0.f, 0.f};
    for (int e0 = beg; e0 < end; e0 += 32) {
#pragma unroll
        for (int j = 0; j < 4; ++j) {
            int e = e0 + 8 * j + grp;
            float m = (e < end) ? 1.f : 0.f;
            int ec = (e < end) ? e : (end - 1);
            int u = col[ec] & 0xFFFF;
            float4 r = *((const float4*)(C + (size_t)u * D) + li);
            const __half2* hp = (const __half2*)&r;
            float2 f0 = __half22float2(hp[0]);
            float2 f1 = __half22float2(hp[1]);
            float2 f2 = __half22float2(hp[2]);
            float2 f3 = __half22float2(hp[3]);
            a[0] += m * f0.x; a[1] += m * f0.y; a[2] += m * f1.x; a[3] += m * f1.y;
            a[4] += m * f2.x; a[5] += m * f2.y; a[6] += m * f3.x; a[7] += m * f3.y;
        }
    }
#pragma unroll
    for (int k = 0; k < 8; ++k) {
        a[k] += __shfl_xor(a[k], 8);
        a[k] += __shfl_xor(a[k], 16);
        a[k] += __shfl_xor(a[k], 32);
    }
    if (grp == 0) {
        float4 rs = *((const float4*)(C + (size_t)v * D) + li);   // self term
        const __half2* sp = (const __half2*)&rs;
        float2 s0 = __half22float2(sp[0]);
        float2 s1 = __half22float2(sp[1]);
        float2 s2 = __half22float2(sp[2]);
        float2 s3 = __half22float2(sp[3]);
        float4 bb0 = ((const float4*)b1)[li * 2];
        float4 bb1 = ((const float4*)b1)[li * 2 + 1];
        float4 o;
        ((__half2*)&o)[0] = __floats2half2_rn(fmaxf(s0.x + a[0] + bb0.x, 0.f),
                                              fmaxf(s0.y + a[1] + bb0.y, 0.f));
        ((__half2*)&o)[1] = __floats2half2_rn(fmaxf(s1.x + a[2] + bb0.z, 0.f),
                                              fmaxf(s1.y + a[3] + bb0.w, 0.f));
        ((__half2*)&o)[2] = __floats2half2_rn(fmaxf(s2.x + a[4] + bb1.x, 0.f),
                                              fmaxf(s2.y + a[5] + bb1.y, 0.f));
        ((__half2*)&o)[3] = __floats2half2_rn(fmaxf(s3.x + a[6] + bb1.z, 0.f),
                                              fmaxf(s3.y + a[7] + bb1.w, 0.f));
        ((float4*)(t + (size_t)v * D))[li] = o;
    }
}

// ===== pooling: 16 waves/graph, half2 reads, row-parity split + LDS tree reduce =====

__global__ __launch_bounds__(1024) void pool_final_kernel(
    const __half* __restrict__ h1, const __half* __restrict__ h2,
    const __half* __restrict__ h3,
    const int* __restrict__ batch, int N,
    const float* __restrict__ W1, const float* __restrict__ W2,
    const float* __restrict__ W3, float* __restrict__ out, int G) {
    __shared__ float r1[16][64];
    __shared__ float r2[16][64];
    __shared__ float r3[16][64];
    int g = blockIdx.x;
    int tid = threadIdx.x;
    int w = tid >> 6, lane = tid & 63;
    int half = lane >> 5, lc = lane & 31;   // lane covers cols 2lc,2lc+1 of row-parity `half`

    int lo = 0, hi = N;
    while (lo < hi) { int mid = (lo + hi) >> 1; if (batch[mid] < g) lo = mid + 1; else hi = mid; }
    int beg = lo;
    hi = N;
    while (lo < hi) { int mid = (lo + hi) >> 1; if (batch[mid] < g + 1) lo = mid + 1; else hi = mid; }
    int end = lo;

    float s1x = 0.f, s1y = 0.f, s2x = 0.f, s2y = 0.f, s3x = 0.f, s3y = 0.f;
    for (int v = beg + 2 * w + half; v < end; v += 32) {
        size_t ro = (size_t)v * D;
        float2 f1 = __half22float2(((const __half2*)(h1 + ro))[lc]);
        float2 f2 = __half22float2(((const __half2*)(h2 + ro))[lc]);
        float2 f3 = __half22float2(((const __half2*)(h3 + ro))[lc]);
        s1x += f1.x; s1y += f1.y;
        s2x += f2.x; s2y += f2.y;
        s3x += f3.x; s3y += f3.y;
    }
    // combine row parities (lane ^ 32 holds the other parity, same columns)
    s1x += __shfl_xor(s1x, 32); s1y += __shfl_xor(s1y, 32);
    s2x += __shfl_xor(s2x, 32); s2y += __shfl_xor(s2y, 32);
    s3x += __shfl_xor(s3x, 32); s3y += __shfl_xor(s3y, 32);
    if (half == 0) {
        ((float2*)r1[w])[lc] = make_float2(s1x, s1y);
        ((float2*)r2[w])[lc] = make_float2(s2x, s2y);
        ((float2*)r3[w])[lc] = make_float2(s3x, s3y);
    }
    __syncthreads();
#pragma unroll
    for (int stride = 8; stride >= 1; stride >>= 1) {
        if (w < stride) {
            r1[w][lane] += r1[w + stride][lane];
            r2[w][lane] += r2[w + stride][lane];
            r3[w][lane] += r3[w + stride][lane];
        }
        __syncthreads();
    }
    if (w == 0) {
        float inv = 1.f / fmaxf((float)(end - beg), 1.f);
        float p1 = r1[0][lane] * inv, p2 = r2[0][lane] * inv, p3 = r3[0][lane] * inv;
        float acc = 0.f;
#pragma unroll
        for (int k = 0; k < D; ++k) {
            acc += __shfl(p1, k) * W1[k * D + lane]
                 + __shfl(p2, k) * W2[k * D + lane]
                 + __shfl(p3, k) * W3[k * D + lane];
        }
        out[(size_t)g * D + lane] = fmaxf(acc, 0.f);
    }
}

// ================= launch =================

static inline size_t align256(size_t x) { return (x + 255) & ~(size_t)255; }

extern "C" void kernel_launch(void* const* d_in, const int* in_sizes, int n_in,
                              void* d_out, int out_size, void* d_ws, size_t ws_size,
                              hipStream_t stream) {
    const int* x      = (const int*)d_in[0];
    const int* ei     = (const int*)d_in[1];
    const int* batch  = (const int*)d_in[2];
    const float* emb  = (const float*)d_in[3];
    const float* Wgcn = (const float*)d_in[4];
    const float* Wsl  = (const float*)d_in[5];
    const float* Wsr  = (const float*)d_in[6];
    const float* Wg1  = (const float*)d_in[7];
    const float* bg1  = (const float*)d_in[8];
    const float* Wg2  = (const float*)d_in[9];
    const float* bg2  = (const float*)d_in[10];
    const float* Wp1  = (const float*)d_in[11];
    const float* Wp2  = (const float*)d_in[12];
    const float* Wp3  = (const float*)d_in[13];
    float* out = (float*)d_out;

    const int N = in_sizes[0];
    const int E = in_sizes[1] / 2;
    const int V = in_sizes[3] / D;
    const int G = out_size / D;
    const int* src = ei;
    const int* dst = ei + E;
    const int NBUCK = (N + 255) >> 8;

    // workspace layout
    char* base = (char*)d_ws;
    size_t off = 0;
    float* embW       = (float*)(base + off); off = align256(off + (size_t)V * D * 4);
    int* bucketFill   = (int*)(base + off);   off = align256(off + 256 * 4);
    int* rowbeg       = (int*)(base + off);   off = align256(off + (size_t)N * 4);
    int* rowend       = (int*)(base + off);   off = align256(off + (size_t)N * 4);
    int* ebuf         = (int*)(base + off);   off = align256(off + (size_t)NBUCK * ECAP * 4);
    int* col          = (int*)(base + off);   off = align256(off + (size_t)NBUCK * ECAP * 4);
    __half* h1        = (__half*)(base + off); off = align256(off + (size_t)N * D * 2);
    __half* h2        = (__half*)(base + off); off = align256(off + (size_t)N * D * 2);
    __half* h3        = (__half*)(base + off); off = align256(off + (size_t)N * D * 2);
    __half* Ah        = (__half*)(base + off); off = align256(off + (size_t)N * D * 2);
    __half* B         = (__half*)(base + off); off = align256(off + (size_t)N * D * 2);
    (void)ws_size;

    __half* Ch = Ah;  // reuse: Ah dead after sage_agg
    __half* t  = B;   // reuse: B dead after sage_agg

    hipMemsetAsync(bucketFill, 0, 256 * 4, stream);

    // fused: embW = emb @ Wgcn (blocks [0,NG)) + padded-bucket edge scatter (rest)
    const int NG = (V + 63) / 64;
    const int NTILE = (E + K3E - 1) / K3E;
    embw_scatter_kernel<<<NG + NTILE, 256, 0, stream>>>(emb, V, Wgcn, embW, NG,
                                                        src, dst, x, bucketFill, ebuf, E);

    // CSR build (per-bucket) then GCN gather at full occupancy -> h1 (fp16)
    csr_build_kernel<<<NBUCK, 1024, 0, stream>>>(ebuf, bucketFill, rowbeg, rowend, col, N);
    gcn_gather_kernel<<<(N + 3) / 4, 256, 0, stream>>>(rowbeg, rowend, col, embW, h1, N);

    // SAGE: Ah = fp16(h1@Wl), B = fp16(h1@Wr), then fused agg epilogue -> h2 (fp16)
    int gb = (N + 63) / 64;
    gemm64h_kernel<<<gb, 256, 0, stream>>>(h1, N, Wsl, Wsr, nullptr, 0, Ah, B);
    sage_agg_kernel<<<(N + 3) / 4, 256, 0, stream>>>(rowbeg, rowend, col, Ah, B, h2, N);

    // GIN: Ch = fp16(h2@W1), t = relu(C + agg(C) + b1), h3 = fp16(relu(t@W2 + b2))
    gemm64h_kernel<<<gb, 256, 0, stream>>>(h2, N, Wg1, nullptr, nullptr, 0, Ch, nullptr);
    gin_agg_kernel<<<(N + 3) / 4, 256, 0, stream>>>(rowbeg, rowend, col, Ch, bg1, t, N);
    gemm64h_kernel<<<gb, 256, 0, stream>>>(t, N, Wg2, nullptr, bg2, 1, h3, nullptr);

    // pooling (16 waves/graph, half2 reads, LDS reduce)
    pool_final_kernel<<<G, 1024, 0, stream>>>(h1, h2, h3, batch, N, Wp1, Wp2, Wp3, out, G);
}

// Round 15
// 220.792 us; speedup vs baseline: 4.8935x; 1.0562x over previous
//
#include <hip/hip_runtime.h>
#include <hip/hip_bf16.h>
#include <hip/hip_fp16.h>

#define D 64
#define K3E 4096
#define ECAP 6144   // slots per 256-node bucket (mean fill 4082, sigma 64 -> 32 sigma headroom)

// Edge word packing (requires N <= 65536, V <= 128 — true for this problem):
//   bits [0:15]  = src node
//   bits [16:22] = x[src]   (vocab id)
//   bits [23:30] = dst & 255 (node index within its 256-node bucket)
//
// Padded-bucket CSR: bucket b owns ebuf/col slots [b*ECAP, b*ECAP + fill_b).
// LESSONS (measured):
//  R6/R12/R13: ALL coupling of GATHER with downstream compute loses (latency
//    death). Gathers live in their own 50k-wave kernels. Block-local GEMM
//    chaining (no gathers, no cross-block deps) is a different thing — R15.
//  R2: guarded (skipped) loads lose to clamped loads — MLP beats issue-waste.
//  R14: float4 (16B/lane) agg gathers: -3.5us, kept.
//  R15: GIN aggregate-first (linearity): z = h2 + sum_nb(h2) gather, then one
//    kernel chains z@Wg1 and t@Wg2 block-locally (t tile reused in At LDS).
//    3 GIN dispatches -> 2; t roundtrip (12.8 MB) eliminated.

// ===== fused front-end: blocks [0,NG) compute embW = emb @ Wgcn (fp32);
//       blocks [NG,..) scatter edges into padded bucket regions. =====

__global__ __launch_bounds__(256) void embw_scatter_kernel(
    const float* __restrict__ emb, int nrows,
    const float* __restrict__ W1, float* __restrict__ embW, int NG,
    const int* __restrict__ src, const int* __restrict__ dst,
    const int* __restrict__ x,
    int* __restrict__ bucketFill, int* __restrict__ ebuf, int E)
{
    __shared__ union SM {
        struct { float At[64][68]; float Ws1[64][64]; } g;
        struct { int uu[K3E]; unsigned char bb[K3E]; int hist[256]; int resBase[256]; } s;
    } sm;
    int t = threadIdx.x;

    if ((int)blockIdx.x >= NG) {
        // ---- scatter half: one 4096-edge tile per block ----
        int bid = blockIdx.x - NG;
        int* uu = sm.s.uu;
        unsigned char* bb = sm.s.bb;
        int* hist = sm.s.hist;
        int* resBase = sm.s.resBase;
        hist[t] = 0;
        __syncthreads();
        int e0 = bid * K3E;
        int cnt = E - e0; if (cnt > K3E) cnt = K3E;
        for (int i = t; i < cnt; i += 256) {
            int e = e0 + i;
            int s = src[e];
            int d = dst[e];
            int xs = x[s];
            uu[i] = s | (xs << 16) | ((d & 255) << 23);
            int b = d >> 8;
            bb[i] = (unsigned char)b;
            atomicAdd(&hist[b], 1);
        }
        __syncthreads();
        int c = hist[t];
        if (c) resBase[t] = t * ECAP + atomicAdd(&bucketFill[t], c);
        __syncthreads();
        hist[t] = 0;
        __syncthreads();
        for (int i = t; i < cnt; i += 256) {
            int b = bb[i];
            int r = atomicAdd(&hist[b], 1);
            int idx = resBase[b] + r;
            if (idx < (b + 1) * ECAP) ebuf[idx] = uu[i];   // overflow guard (never hit at 32 sigma)
        }
        return;
    }

    // ---- embW GEMM half (fp32, V rows) ----
    {
        const float4* w1v = (const float4*)W1;
        float4* s1 = (float4*)&sm.g.Ws1[0][0];
        for (int i = t; i < 1024; i += 256) s1[i] = w1v[i];
    }
    int r0 = blockIdx.x * 64;
    for (int i = t; i < 1024; i += 256) {
        int r = i >> 4, c4 = i & 15;
        int gr = r0 + r; if (gr >= nrows) gr = nrows - 1;
        float4 v = ((const float4*)(emb + (size_t)gr * D))[c4];
        float* dp = &sm.g.At[r][c4 * 4];
        dp[0] = v.x; dp[1] = v.y; dp[2] = v.z; dp[3] = v.w;
    }
    __syncthreads();

    int cg = t & 15;
    int rg = t >> 4;
    float acc1[4][4] = {{0.f}};

    for (int k0 = 0; k0 < 64; k0 += 4) {
        float4 a[4], w1[4];
#pragma unroll
        for (int i = 0; i < 4; ++i) a[i] = *(const float4*)&sm.g.At[4 * rg + i][k0];
#pragma unroll
        for (int j = 0; j < 4; ++j) w1[j] = *(const float4*)&sm.g.Ws1[k0 + j][cg * 4];
#pragma unroll
        for (int i = 0; i < 4; ++i) {
            float av[4] = {a[i].x, a[i].y, a[i].z, a[i].w};
#pragma unroll
            for (int kk = 0; kk < 4; ++kk) {
                acc1[i][0] += av[kk] * w1[kk].x;
                acc1[i][1] += av[kk] * w1[kk].y;
                acc1[i][2] += av[kk] * w1[kk].z;
                acc1[i][3] += av[kk] * w1[kk].w;
            }
        }
    }
#pragma unroll
    for (int i = 0; i < 4; ++i) {
        int gr = r0 + 4 * rg + i;
        if (gr < nrows) {
            float4 o;
            o.x = acc1[i][0]; o.y = acc1[i][1]; o.z = acc1[i][2]; o.w = acc1[i][3];
            ((float4*)(embW + (size_t)gr * D))[cg] = o;
        }
    }
}

// ===== per-bucket exact CSR build (LDS 27 KB) =====

__global__ __launch_bounds__(1024) void csr_build_kernel(
    const int* __restrict__ ebuf, const int* __restrict__ bucketFill,
    int* __restrict__ rowbeg, int* __restrict__ rowend, int* __restrict__ col,
    int N)
{
    __shared__ int eLds[ECAP];       // 24 KB
    __shared__ int hist[256];        // 1 KB
    __shared__ int sc[256];          // 1 KB
    int b = blockIdx.x, t = threadIdx.x;
    int base = b * ECAP;
    int m = bucketFill[b]; if (m > ECAP) m = ECAP;

    if (t < 256) hist[t] = 0;
    __syncthreads();

    for (int i = t; i < m; i += 1024) {
        int u = ebuf[base + i];
        eLds[i] = u;
        atomicAdd(&hist[(u >> 23) & 255], 1);
    }
    __syncthreads();

    int v = (t < 256) ? hist[t] : 0;
    if (t < 256) sc[t] = v;
    __syncthreads();
    for (int off = 1; off < 256; off <<= 1) {
        int w = (t >= off && t < 256) ? sc[t - off] : 0;
        __syncthreads();
        if (t < 256) sc[t] += w;
        __syncthreads();
    }
    if (t < 256) {
        int excl = sc[t] - v;
        int node = (b << 8) + t;
        if (node < N) {
            rowbeg[node] = base + excl;
            rowend[node] = base + sc[t];
        }
        hist[t] = excl;   // running local cursor
    }
    __syncthreads();

    for (int i = t; i < m; i += 1024) {
        int u = eLds[i];
        int dl = (u >> 23) & 255;
        int r = atomicAdd(&hist[dl], 1);
        col[base + r] = u;
    }
}

// ===== GCN gather at full occupancy: h1[v] = relu(sum_nb embW[x[u]]) =====

__global__ __launch_bounds__(256) void gcn_gather_kernel(
    const int* __restrict__ rowbeg, const int* __restrict__ rowend,
    const int* __restrict__ col,
    const float* __restrict__ embW,
    __half* __restrict__ h1, int N)
{
    int tid = threadIdx.x;
    int lane = tid & 63;
    int grp = lane >> 4, li = lane & 15;
    int v = blockIdx.x * 4 + (tid >> 6);
    if (v >= N) return;
    int beg = rowbeg[v], end = rowend[v];
    float a0 = 0.f, a1 = 0.f, a2 = 0.f, a3 = 0.f;
    for (int e0 = beg; e0 < end; e0 += 32) {
#pragma unroll
        for (int j = 0; j < 8; ++j) {
            int e = e0 + 4 * j + grp;
            float m = (e < end) ? 1.f : 0.f;
            int ec = (e < end) ? e : (end - 1);
            int xu = (col[ec] >> 16) & 0x7F;
            float4 f = *((const float4*)(embW + (size_t)xu * D) + li);
            a0 += m * f.x; a1 += m * f.y; a2 += m * f.z; a3 += m * f.w;
        }
    }
    a0 += __shfl_xor(a0, 16); a0 += __shfl_xor(a0, 32);
    a1 += __shfl_xor(a1, 16); a1 += __shfl_xor(a1, 32);
    a2 += __shfl_xor(a2, 16); a2 += __shfl_xor(a2, 32);
    a3 += __shfl_xor(a3, 16); a3 += __shfl_xor(a3, 32);
    if (grp == 0) {
        float2 oh;
        *(__half2*)&oh.x = __floats2half2_rn(fmaxf(a0, 0.f), fmaxf(a1, 0.f));
        *(__half2*)&oh.y = __floats2half2_rn(fmaxf(a2, 0.f), fmaxf(a3, 0.f));
        ((float2*)(h1 + (size_t)v * D))[li] = oh;
    }
}

// ===== fp16-in / fp16-out GEMM (fp32 LDS + fp32 accumulate), optional dual output =====

__global__ __launch_bounds__(256) void gemm64h_kernel(
    const __half* __restrict__ in, int nrows,
    const float* __restrict__ W1, const float* __restrict__ W2,
    const float* __restrict__ bias, int do_relu,
    __half* __restrict__ out1, __half* __restrict__ out2)
{
    __shared__ float At[64][68];
    __shared__ float Ws1[64][64];
    __shared__ float Ws2[64][64];
    int tid = threadIdx.x;
    {
        const float4* w1v = (const float4*)W1;
        float4* s1 = (float4*)&Ws1[0][0];
        for (int i = tid; i < 1024; i += 256) s1[i] = w1v[i];
        if (W2) {
            const float4* w2v = (const float4*)W2;
            float4* s2 = (float4*)&Ws2[0][0];
            for (int i = tid; i < 1024; i += 256) s2[i] = w2v[i];
        }
    }
    int r0 = blockIdx.x * 64;
    for (int i = tid; i < 512; i += 256) {
        int r = i >> 3, c8 = i & 7;
        int gr = r0 + r; if (gr >= nrows) gr = nrows - 1;
        float4 hv = ((const float4*)(in + (size_t)gr * D))[c8];
        const __half2* hp = (const __half2*)&hv;
        float* dp = &At[r][c8 * 8];
        float2 f;
        f = __half22float2(hp[0]); dp[0] = f.x; dp[1] = f.y;
        f = __half22float2(hp[1]); dp[2] = f.x; dp[3] = f.y;
        f = __half22float2(hp[2]); dp[4] = f.x; dp[5] = f.y;
        f = __half22float2(hp[3]); dp[6] = f.x; dp[7] = f.y;
    }
    __syncthreads();

    int cg = tid & 15;
    int rg = tid >> 4;
    float acc1[4][4] = {{0.f}}, acc2[4][4] = {{0.f}};

    for (int k0 = 0; k0 < 64; k0 += 4) {
        float4 a[4], w1[4];
#pragma unroll
        for (int i = 0; i < 4; ++i) a[i] = *(const float4*)&At[4 * rg + i][k0];
#pragma unroll
        for (int j = 0; j < 4; ++j) w1[j] = *(const float4*)&Ws1[k0 + j][cg * 4];
#pragma unroll
        for (int i = 0; i < 4; ++i) {
            float av[4] = {a[i].x, a[i].y, a[i].z, a[i].w};
#pragma unroll
            for (int kk = 0; kk < 4; ++kk) {
                acc1[i][0] += av[kk] * w1[kk].x;
                acc1[i][1] += av[kk] * w1[kk].y;
                acc1[i][2] += av[kk] * w1[kk].z;
                acc1[i][3] += av[kk] * w1[kk].w;
            }
        }
        if (W2) {
            float4 w2[4];
#pragma unroll
            for (int j = 0; j < 4; ++j) w2[j] = *(const float4*)&Ws2[k0 + j][cg * 4];
#pragma unroll
            for (int i = 0; i < 4; ++i) {
                float av[4] = {a[i].x, a[i].y, a[i].z, a[i].w};
#pragma unroll
                for (int kk = 0; kk < 4; ++kk) {
                    acc2[i][0] += av[kk] * w2[kk].x;
                    acc2[i][1] += av[kk] * w2[kk].y;
                    acc2[i][2] += av[kk] * w2[kk].z;
                    acc2[i][3] += av[kk] * w2[kk].w;
                }
            }
        }
    }

    float4 bv = make_float4(0.f, 0.f, 0.f, 0.f);
    if (bias) bv = ((const float4*)bias)[cg];
#pragma unroll
    for (int i = 0; i < 4; ++i) {
        int gr = r0 + 4 * rg + i;
        if (gr < nrows) {
            float ox = acc1[i][0] + bv.x, oy = acc1[i][1] + bv.y;
            float oz = acc1[i][2] + bv.z, ow = acc1[i][3] + bv.w;
            if (do_relu) {
                ox = fmaxf(ox, 0.f); oy = fmaxf(oy, 0.f);
                oz = fmaxf(oz, 0.f); ow = fmaxf(ow, 0.f);
            }
            float2 oh;
            *(__half2*)&oh.x = __floats2half2_rn(ox, oy);
            *(__half2*)&oh.y = __floats2half2_rn(oz, ow);
            ((float2*)(out1 + (size_t)gr * D))[cg] = oh;
            if (out2) {
                float2 o2;
                *(__half2*)&o2.x = __floats2half2_rn(acc2[i][0], acc2[i][1]);
                *(__half2*)&o2.y = __floats2half2_rn(acc2[i][2], acc2[i][3]);
                ((float2*)(out2 + (size_t)gr * D))[cg] = o2;
            }
        }
    }
}

// ===== SAGE epilogue: h2 = relu( agg(A)/deg + B ) — float4 (16B/lane) gathers =====

__global__ __launch_bounds__(256) void sage_agg_kernel(const int* __restrict__ rowbeg,
                                                       const int* __restrict__ rowend,
                                                       const int* __restrict__ col,
                                                       const __half* __restrict__ A,
                                                       const __half* __restrict__ B,
                                                       __half* __restrict__ h2, int N) {
    int tid = threadIdx.x;
    int lane = tid & 63;
    int grp = lane >> 3, li = lane & 7;
    int v = blockIdx.x * 4 + (tid >> 6);
    if (v >= N) return;
    int beg = rowbeg[v], end = rowend[v];
    float a[8] = {0.f, 0.f, 0.f, 0.f, 0.f, 0.f, 0.f, 0.f};
    for (int e0 = beg; e0 < end; e0 += 32) {
#pragma unroll
        for (int j = 0; j < 4; ++j) {
            int e = e0 + 8 * j + grp;
            float m = (e < end) ? 1.f : 0.f;
            int ec = (e < end) ? e : (end - 1);
            int u = col[ec] & 0xFFFF;
            float4 r = *((const float4*)(A + (size_t)u * D) + li);
            const __half2* hp = (const __half2*)&r;
            float2 f0 = __half22float2(hp[0]);
            float2 f1 = __half22float2(hp[1]);
            float2 f2 = __half22float2(hp[2]);
            float2 f3 = __half22float2(hp[3]);
            a[0] += m * f0.x; a[1] += m * f0.y; a[2] += m * f1.x; a[3] += m * f1.y;
            a[4] += m * f2.x; a[5] += m * f2.y; a[6] += m * f3.x; a[7] += m * f3.y;
        }
    }
#pragma unroll
    for (int k = 0; k < 8; ++k) {
        a[k] += __shfl_xor(a[k], 8);
        a[k] += __shfl_xor(a[k], 16);
        a[k] += __shfl_xor(a[k], 32);
    }
    if (grp == 0) {
        float inv = 1.f / fmaxf((float)(end - beg), 1.f);
        float4 br = *((const float4*)(B + (size_t)v * D) + li);
        const __half2* bp = (const __half2*)&br;
        float2 b0 = __half22float2(bp[0]);
        float2 b1 = __half22float2(bp[1]);
        float2 b2 = __half22float2(bp[2]);
        float2 b3 = __half22float2(bp[3]);
        float4 o;
        ((__half2*)&o)[0] = __floats2half2_rn(fmaxf(a[0] * inv + b0.x, 0.f),
                                              fmaxf(a[1] * inv + b0.y, 0.f));
        ((__half2*)&o)[1] = __floats2half2_rn(fmaxf(a[2] * inv + b1.x, 0.f),
                                              fmaxf(a[3] * inv + b1.y, 0.f));
        ((__half2*)&o)[2] = __floats2half2_rn(fmaxf(a[4] * inv + b2.x, 0.f),
                                              fmaxf(a[5] * inv + b2.y, 0.f));
        ((__half2*)&o)[3] = __floats2half2_rn(fmaxf(a[6] * inv + b3.x, 0.f),
                                              fmaxf(a[7] * inv + b3.y, 0.f));
        ((float4*)(h2 + (size_t)v * D))[li] = o;
    }
}

// ===== GIN aggregate-first: z = h2 + sum_nb(h2) — float4 gathers, no bias/relu =====

__global__ __launch_bounds__(256) void gin_z_agg_kernel(const int* __restrict__ rowbeg,
                                                        const int* __restrict__ rowend,
                                                        const int* __restrict__ col,
                                                        const __half* __restrict__ h2,
                                                        __half* __restrict__ z, int N) {
    int tid = threadIdx.x;
    int lane = tid & 63;
    int grp = lane >> 3, li = lane & 7;
    int v = blockIdx.x * 4 + (tid >> 6);
    if (v >= N) return;
    int beg = rowbeg[v], end = rowend[v];
    float a[8] = {0.f, 0.f, 0.f, 0.f, 0.f, 0.f, 0.f, 0.f};
    for (int e0 = beg; e0 < end; e0 += 32) {
#pragma unroll
        for (int j = 0; j < 4; ++j) {
            int e = e0 + 8 * j + grp;
            float m = (e < end) ? 1.f : 0.f;
            int ec = (e < end) ? e : (end - 1);
            int u = col[ec] & 0xFFFF;
            float4 r = *((const float4*)(h2 + (size_t)u * D) + li);
            const __half2* hp = (const __half2*)&r;
            float2 f0 = __half22float2(hp[0]);
            float2 f1 = __half22float2(hp[1]);
            float2 f2 = __half22float2(hp[2]);
            float2 f3 = __half22float2(hp[3]);
            a[0] += m * f0.x; a[1] += m * f0.y; a[2] += m * f1.x; a[3] += m * f1.y;
            a[4] += m * f2.x; a[5] += m * f2.y; a[6] += m * f3.x; a[7] += m * f3.y;
        }
    }
#pragma unroll
    for (int k = 0; k < 8; ++k) {
        a[k] += __shfl_xor(a[k], 8);
        a[k] += __shfl_xor(a[k], 16);
        a[k] += __shfl_xor(a[k], 32);
    }
    if (grp == 0) {
        float4 rs = *((const float4*)(h2 + (size_t)v * D) + li);   // self term
        const __half2* sp = (const __half2*)&rs;
        float2 s0 = __half22float2(sp[0]);
        float2 s1 = __half22float2(sp[1]);
        float2 s2 = __half22float2(sp[2]);
        float2 s3 = __half22float2(sp[3]);
        float4 o;
        ((__half2*)&o)[0] = __floats2half2_rn(s0.x + a[0], s0.y + a[1]);
        ((__half2*)&o)[1] = __floats2half2_rn(s1.x + a[2], s1.y + a[3]);
        ((__half2*)&o)[2] = __floats2half2_rn(s2.x + a[4], s2.y + a[5]);
        ((__half2*)&o)[3] = __floats2half2_rn(s3.x + a[6], s3.y + a[7]);
        ((float4*)(z + (size_t)v * D))[li] = o;
    }
}

// ===== GIN MLP: h3 = relu( relu(z@Wg1+b1) @ Wg2 + b2 ) — two chained GEMMs,
//       block-local (t tile written back into At between barriers). =====

__global__ __launch_bounds__(256) void gin_mlp_kernel(
    const __half* __restrict__ z, int nrows,
    const float* __restrict__ Wg1, const float* __restrict__ b1,
    const float* __restrict__ Wg2, const float* __restrict__ b2,
    __half* __restrict__ h3)
{
    __shared__ float At[64][68];     // 17.4 KB (z tile, then t tile in-place)
    __shared__ float Ws1[64][64];    // 16 KB
    __shared__ float Ws2[64][64];    // 16 KB
    int tid = threadIdx.x;
    {
        const float4* w1v = (const float4*)Wg1;
        const float4* w2v = (const float4*)Wg2;
        float4* s1 = (float4*)&Ws1[0][0];
        float4* s2 = (float4*)&Ws2[0][0];
        for (int i = tid; i < 1024; i += 256) { s1[i] = w1v[i]; s2[i] = w2v[i]; }
    }
    int r0 = blockIdx.x * 64;
    for (int i = tid; i < 512; i += 256) {
        int r = i >> 3, c8 = i & 7;
        int gr = r0 + r; if (gr >= nrows) gr = nrows - 1;
        float4 hv = ((const float4*)(z + (size_t)gr * D))[c8];
        const __half2* hp = (const __half2*)&hv;
        float* dp = &At[r][c8 * 8];
        float2 f;
        f = __half22float2(hp[0]); dp[0] = f.x; dp[1] = f.y;
        f = __half22float2(hp[1]); dp[2] = f.x; dp[3] = f.y;
        f = __half22float2(hp[2]); dp[4] = f.x; dp[5] = f.y;
        f = __half22float2(hp[3]); dp[6] = f.x; dp[7] = f.y;
    }
    __syncthreads();

    int cg = tid & 15;
    int rg = tid >> 4;

    // ---- GEMM 1: t = relu(z@Wg1 + b1) ----
    float acc[4][4] = {{0.f}};
    for (int k0 = 0; k0 < 64; k0 += 4) {
        float4 a[4], w1[4];
#pragma unroll
        for (int i = 0; i < 4; ++i) a[i] = *(const float4*)&At[4 * rg + i][k0];
#pragma unroll
        for (int j = 0; j < 4; ++j) w1[j] = *(const float4*)&Ws1[k0 + j][cg * 4];
#pragma unroll
        for (int i = 0; i < 4; ++i) {
            float av[4] = {a[i].x, a[i].y, a[i].z, a[i].w};
#pragma unroll
            for (int kk = 0; kk < 4; ++kk) {
                acc[i][0] += av[kk] * w1[kk].x;
                acc[i][1] += av[kk] * w1[kk].y;
                acc[i][2] += av[kk] * w1[kk].z;
                acc[i][3] += av[kk] * w1[kk].w;
            }
        }
    }
    float4 bv1 = ((const float4*)b1)[cg];
    __syncthreads();   // all reads of At (z tile) complete
#pragma unroll
    for (int i = 0; i < 4; ++i) {
        float* dp = &At[4 * rg + i][cg * 4];
        dp[0] = fmaxf(acc[i][0] + bv1.x, 0.f);
        dp[1] = fmaxf(acc[i][1] + bv1.y, 0.f);
        dp[2] = fmaxf(acc[i][2] + bv1.z, 0.f);
        dp[3] = fmaxf(acc[i][3] + bv1.w, 0.f);
    }
    __syncthreads();   // t tile fully written

    // ---- GEMM 2: h3 = relu(t@Wg2 + b2) ----
    float acc2[4][4] = {{0.f}};
    for (int k0 = 0; k0 < 64; k0 += 4) {
        float4 a[4], w2[4];
#pragma unroll
        for (int i = 0; i < 4; ++i) a[i] = *(const float4*)&At[4 * rg + i][k0];
#pragma unroll
        for (int j = 0; j < 4; ++j) w2[j] = *(const float4*)&Ws2[k0 + j][cg * 4];
#pragma unroll
        for (int i = 0; i < 4; ++i) {
            float av[4] = {a[i].x, a[i].y, a[i].z, a[i].w};
#pragma unroll
            for (int kk = 0; kk < 4; ++kk) {
                acc2[i][0] += av[kk] * w2[kk].x;
                acc2[i][1] += av[kk] * w2[kk].y;
                acc2[i][2] += av[kk] * w2[kk].z;
                acc2[i][3] += av[kk] * w2[kk].w;
            }
        }
    }
    float4 bv2 = ((const float4*)b2)[cg];
#pragma unroll
    for (int i = 0; i < 4; ++i) {
        int gr = r0 + 4 * rg + i;
        if (gr < nrows) {
            float2 oh;
            *(__half2*)&oh.x = __floats2half2_rn(fmaxf(acc2[i][0] + bv2.x, 0.f),
                                                 fmaxf(acc2[i][1] + bv2.y, 0.f));
            *(__half2*)&oh.y = __floats2half2_rn(fmaxf(acc2[i][2] + bv2.z, 0.f),
                                                 fmaxf(acc2[i][3] + bv2.w, 0.f));
            ((float2*)(h3 + (size_t)gr * D))[cg] = oh;
        }
    }
}

// ===== pooling: 16 waves/graph, half2 reads, row-parity split + LDS tree reduce =====

__global__ __launch_bounds__(1024) void pool_final_kernel(
    const __half* __restrict__ h1, const __half* __restrict__ h2,
    const __half* __restrict__ h3,
    const int* __restrict__ batch, int N,
    const float* __restrict__ W1, const float* __restrict__ W2,
    const float* __restrict__ W3, float* __restrict__ out, int G) {
    __shared__ float r1[16][64];
    __shared__ float r2[16][64];
    __shared__ float r3[16][64];
    int g = blockIdx.x;
    int tid = threadIdx.x;
    int w = tid >> 6, lane = tid & 63;
    int half = lane >> 5, lc = lane & 31;   // lane covers cols 2lc,2lc+1 of row-parity `half`

    int lo = 0, hi = N;
    while (lo < hi) { int mid = (lo + hi) >> 1; if (batch[mid] < g) lo = mid + 1; else hi = mid; }
    int beg = lo;
    hi = N;
    while (lo < hi) { int mid = (lo + hi) >> 1; if (batch[mid] < g + 1) lo = mid + 1; else hi = mid; }
    int end = lo;

    float s1x = 0.f, s1y = 0.f, s2x = 0.f, s2y = 0.f, s3x = 0.f, s3y = 0.f;
    for (int v = beg + 2 * w + half; v < end; v += 32) {
        size_t ro = (size_t)v * D;
        float2 f1 = __half22float2(((const __half2*)(h1 + ro))[lc]);
        float2 f2 = __half22float2(((const __half2*)(h2 + ro))[lc]);
        float2 f3 = __half22float2(((const __half2*)(h3 + ro))[lc]);
        s1x += f1.x; s1y += f1.y;
        s2x += f2.x; s2y += f2.y;
        s3x += f3.x; s3y += f3.y;
    }
    // combine row parities (lane ^ 32 holds the other parity, same columns)
    s1x += __shfl_xor(s1x, 32); s1y += __shfl_xor(s1y, 32);
    s2x += __shfl_xor(s2x, 32); s2y += __shfl_xor(s2y, 32);
    s3x += __shfl_xor(s3x, 32); s3y += __shfl_xor(s3y, 32);
    if (half == 0) {
        ((float2*)r1[w])[lc] = make_float2(s1x, s1y);
        ((float2*)r2[w])[lc] = make_float2(s2x, s2y);
        ((float2*)r3[w])[lc] = make_float2(s3x, s3y);
    }
    __syncthreads();
#pragma unroll
    for (int stride = 8; stride >= 1; stride >>= 1) {
        if (w < stride) {
            r1[w][lane] += r1[w + stride][lane];
            r2[w][lane] += r2[w + stride][lane];
            r3[w][lane] += r3[w + stride][lane];
        }
        __syncthreads();
    }
    if (w == 0) {
        float inv = 1.f / fmaxf((float)(end - beg), 1.f);
        float p1 = r1[0][lane] * inv, p2 = r2[0][lane] * inv, p3 = r3[0][lane] * inv;
        float acc = 0.f;
#pragma unroll
        for (int k = 0; k < D; ++k) {
            acc += __shfl(p1, k) * W1[k * D + lane]
                 + __shfl(p2, k) * W2[k * D + lane]
                 + __shfl(p3, k) * W3[k * D + lane];
        }
        out[(size_t)g * D + lane] = fmaxf(acc, 0.f);
    }
}

// ================= launch =================

static inline size_t align256(size_t x) { return (x + 255) & ~(size_t)255; }

extern "C" void kernel_launch(void* const* d_in, const int* in_sizes, int n_in,
                              void* d_out, int out_size, void* d_ws, size_t ws_size,
                              hipStream_t stream) {
    const int* x      = (const int*)d_in[0];
    const int* ei     = (const int*)d_in[1];
    const int* batch  = (const int*)d_in[2];
    const float* emb  = (const float*)d_in[3];
    const float* Wgcn = (const float*)d_in[4];
    const float* Wsl  = (const float*)d_in[5];
    const float* Wsr  = (const float*)d_in[6];
    const float* Wg1  = (const float*)d_in[7];
    const float* bg1  = (const float*)d_in[8];
    const float* Wg2  = (const float*)d_in[9];
    const float* bg2  = (const float*)d_in[10];
    const float* Wp1  = (const float*)d_in[11];
    const float* Wp2  = (const float*)d_in[12];
    const float* Wp3  = (const float*)d_in[13];
    float* out = (float*)d_out;

    const int N = in_sizes[0];
    const int E = in_sizes[1] / 2;
    const int V = in_sizes[3] / D;
    const int G = out_size / D;
    const int* src = ei;
    const int* dst = ei + E;
    const int NBUCK = (N + 255) >> 8;

    // workspace layout
    char* base = (char*)d_ws;
    size_t off = 0;
    float* embW       = (float*)(base + off); off = align256(off + (size_t)V * D * 4);
    int* bucketFill   = (int*)(base + off);   off = align256(off + 256 * 4);
    int* rowbeg       = (int*)(base + off);   off = align256(off + (size_t)N * 4);
    int* rowend       = (int*)(base + off);   off = align256(off + (size_t)N * 4);
    int* ebuf         = (int*)(base + off);   off = align256(off + (size_t)NBUCK * ECAP * 4);
    int* col          = (int*)(base + off);   off = align256(off + (size_t)NBUCK * ECAP * 4);
    __half* h1        = (__half*)(base + off); off = align256(off + (size_t)N * D * 2);
    __half* h2        = (__half*)(base + off); off = align256(off + (size_t)N * D * 2);
    __half* h3        = (__half*)(base + off); off = align256(off + (size_t)N * D * 2);
    __half* Ah        = (__half*)(base + off); off = align256(off + (size_t)N * D * 2);
    __half* B         = (__half*)(base + off); off = align256(off + (size_t)N * D * 2);
    (void)ws_size;

    __half* z = Ah;   // reuse: Ah dead after sage_agg

    hipMemsetAsync(bucketFill, 0, 256 * 4, stream);

    // fused: embW = emb @ Wgcn (blocks [0,NG)) + padded-bucket edge scatter (rest)
    const int NG = (V + 63) / 64;
    const int NTILE = (E + K3E - 1) / K3E;
    embw_scatter_kernel<<<NG + NTILE, 256, 0, stream>>>(emb, V, Wgcn, embW, NG,
                                                        src, dst, x, bucketFill, ebuf, E);

    // CSR build (per-bucket) then GCN gather at full occupancy -> h1 (fp16)
    csr_build_kernel<<<NBUCK, 1024, 0, stream>>>(ebuf, bucketFill, rowbeg, rowend, col, N);
    gcn_gather_kernel<<<(N + 3) / 4, 256, 0, stream>>>(rowbeg, rowend, col, embW, h1, N);

    // SAGE: Ah = fp16(h1@Wl), B = fp16(h1@Wr), then fused agg epilogue -> h2 (fp16)
    int gb = (N + 63) / 64;
    gemm64h_kernel<<<gb, 256, 0, stream>>>(h1, N, Wsl, Wsr, nullptr, 0, Ah, B);
    sage_agg_kernel<<<(N + 3) / 4, 256, 0, stream>>>(rowbeg, rowend, col, Ah, B, h2, N);

    // GIN aggregate-first: z = h2 + sum_nb(h2), then fused 2-GEMM MLP -> h3
    gin_z_agg_kernel<<<(N + 3) / 4, 256, 0, stream>>>(rowbeg, rowend, col, h2, z, N);
    gin_mlp_kernel<<<gb, 256, 0, stream>>>(z, N, Wg1, bg1, Wg2, bg2, h3);

    // pooling (16 waves/graph, half2 reads, LDS reduce)
    pool_final_kernel<<<G, 1024, 0, stream>>>(h1, h2, h3, batch, N, Wp1, Wp2, Wp3, out, G);
}

// Round 17
// 218.640 us; speedup vs baseline: 4.9417x; 1.0098x over previous
//
#include <hip/hip_runtime.h>
#include <hip/hip_bf16.h>
#include <hip/hip_fp16.h>

#define D 64
#define K3E 4096
#define ECAP 6144   // slots per 256-node bucket (mean fill 4082, sigma 64 -> 32 sigma headroom)

// Edge word packing (requires N <= 65536, V <= 128 — true for this problem):
//   bits [0:15]  = src node
//   bits [16:22] = x[src]   (vocab id)
//   bits [23:30] = dst & 255 (node index within its 256-node bucket)
//
// Padded-bucket CSR: bucket b owns ebuf/col slots [b*ECAP, b*ECAP + fill_b).
// LESSONS (measured):
//  R6/R12/R13: ALL coupling of GATHER with downstream compute loses (latency
//    death). Gathers live in their own 50k-wave kernels.
//  R2: guarded (skipped) loads lose to clamped loads — MLP beats issue-waste.
//  R14: float4 (16B/lane) agg gathers: -3.5us, kept.
//  R15: GIN aggregate-first + block-local 2-GEMM chain: -12.4us. Pattern wins.
//  R16: same for SAGE: s = mean_nb(h1) gather, then h2 = relu(s@Wsl + h1@Wsr)
//    via sequential two-tile staging. Ah/B intermediates (38 MB traffic) gone.

// ===== fused front-end: blocks [0,NG) compute embW = emb @ Wgcn (fp32);
//       blocks [NG,..) scatter edges into padded bucket regions. =====

__global__ __launch_bounds__(256) void embw_scatter_kernel(
    const float* __restrict__ emb, int nrows,
    const float* __restrict__ W1, float* __restrict__ embW, int NG,
    const int* __restrict__ src, const int* __restrict__ dst,
    const int* __restrict__ x,
    int* __restrict__ bucketFill, int* __restrict__ ebuf, int E)
{
    __shared__ union SM {
        struct { float At[64][68]; float Ws1[64][64]; } g;
        struct { int uu[K3E]; unsigned char bb[K3E]; int hist[256]; int resBase[256]; } s;
    } sm;
    int t = threadIdx.x;

    if ((int)blockIdx.x >= NG) {
        // ---- scatter half: one 4096-edge tile per block ----
        int bid = blockIdx.x - NG;
        int* uu = sm.s.uu;
        unsigned char* bb = sm.s.bb;
        int* hist = sm.s.hist;
        int* resBase = sm.s.resBase;
        hist[t] = 0;
        __syncthreads();
        int e0 = bid * K3E;
        int cnt = E - e0; if (cnt > K3E) cnt = K3E;
        for (int i = t; i < cnt; i += 256) {
            int e = e0 + i;
            int s = src[e];
            int d = dst[e];
            int xs = x[s];
            uu[i] = s | (xs << 16) | ((d & 255) << 23);
            int b = d >> 8;
            bb[i] = (unsigned char)b;
            atomicAdd(&hist[b], 1);
        }
        __syncthreads();
        int c = hist[t];
        if (c) resBase[t] = t * ECAP + atomicAdd(&bucketFill[t], c);
        __syncthreads();
        hist[t] = 0;
        __syncthreads();
        for (int i = t; i < cnt; i += 256) {
            int b = bb[i];
            int r = atomicAdd(&hist[b], 1);
            int idx = resBase[b] + r;
            if (idx < (b + 1) * ECAP) ebuf[idx] = uu[i];   // overflow guard (never hit at 32 sigma)
        }
        return;
    }

    // ---- embW GEMM half (fp32, V rows) ----
    {
        const float4* w1v = (const float4*)W1;
        float4* s1 = (float4*)&sm.g.Ws1[0][0];
        for (int i = t; i < 1024; i += 256) s1[i] = w1v[i];
    }
    int r0 = blockIdx.x * 64;
    for (int i = t; i < 1024; i += 256) {
        int r = i >> 4, c4 = i & 15;
        int gr = r0 + r; if (gr >= nrows) gr = nrows - 1;
        float4 v = ((const float4*)(emb + (size_t)gr * D))[c4];
        float* dp = &sm.g.At[r][c4 * 4];
        dp[0] = v.x; dp[1] = v.y; dp[2] = v.z; dp[3] = v.w;
    }
    __syncthreads();

    int cg = t & 15;
    int rg = t >> 4;
    float acc1[4][4] = {{0.f}};

    for (int k0 = 0; k0 < 64; k0 += 4) {
        float4 a[4], w1[4];
#pragma unroll
        for (int i = 0; i < 4; ++i) a[i] = *(const float4*)&sm.g.At[4 * rg + i][k0];
#pragma unroll
        for (int j = 0; j < 4; ++j) w1[j] = *(const float4*)&sm.g.Ws1[k0 + j][cg * 4];
#pragma unroll
        for (int i = 0; i < 4; ++i) {
            float av[4] = {a[i].x, a[i].y, a[i].z, a[i].w};
#pragma unroll
            for (int kk = 0; kk < 4; ++kk) {
                acc1[i][0] += av[kk] * w1[kk].x;
                acc1[i][1] += av[kk] * w1[kk].y;
                acc1[i][2] += av[kk] * w1[kk].z;
                acc1[i][3] += av[kk] * w1[kk].w;
            }
        }
    }
#pragma unroll
    for (int i = 0; i < 4; ++i) {
        int gr = r0 + 4 * rg + i;
        if (gr < nrows) {
            float4 o;
            o.x = acc1[i][0]; o.y = acc1[i][1]; o.z = acc1[i][2]; o.w = acc1[i][3];
            ((float4*)(embW + (size_t)gr * D))[cg] = o;
        }
    }
}

// ===== per-bucket exact CSR build (LDS 27 KB) =====

__global__ __launch_bounds__(1024) void csr_build_kernel(
    const int* __restrict__ ebuf, const int* __restrict__ bucketFill,
    int* __restrict__ rowbeg, int* __restrict__ rowend, int* __restrict__ col,
    int N)
{
    __shared__ int eLds[ECAP];       // 24 KB
    __shared__ int hist[256];        // 1 KB
    __shared__ int sc[256];          // 1 KB
    int b = blockIdx.x, t = threadIdx.x;
    int base = b * ECAP;
    int m = bucketFill[b]; if (m > ECAP) m = ECAP;

    if (t < 256) hist[t] = 0;
    __syncthreads();

    for (int i = t; i < m; i += 1024) {
        int u = ebuf[base + i];
        eLds[i] = u;
        atomicAdd(&hist[(u >> 23) & 255], 1);
    }
    __syncthreads();

    int v = (t < 256) ? hist[t] : 0;
    if (t < 256) sc[t] = v;
    __syncthreads();
    for (int off = 1; off < 256; off <<= 1) {
        int w = (t >= off && t < 256) ? sc[t - off] : 0;
        __syncthreads();
        if (t < 256) sc[t] += w;
        __syncthreads();
    }
    if (t < 256) {
        int excl = sc[t] - v;
        int node = (b << 8) + t;
        if (node < N) {
            rowbeg[node] = base + excl;
            rowend[node] = base + sc[t];
        }
        hist[t] = excl;   // running local cursor
    }
    __syncthreads();

    for (int i = t; i < m; i += 1024) {
        int u = eLds[i];
        int dl = (u >> 23) & 255;
        int r = atomicAdd(&hist[dl], 1);
        col[base + r] = u;
    }
}

// ===== GCN gather at full occupancy: h1[v] = relu(sum_nb embW[x[u]]) =====

__global__ __launch_bounds__(256) void gcn_gather_kernel(
    const int* __restrict__ rowbeg, const int* __restrict__ rowend,
    const int* __restrict__ col,
    const float* __restrict__ embW,
    __half* __restrict__ h1, int N)
{
    int tid = threadIdx.x;
    int lane = tid & 63;
    int grp = lane >> 4, li = lane & 15;
    int v = blockIdx.x * 4 + (tid >> 6);
    if (v >= N) return;
    int beg = rowbeg[v], end = rowend[v];
    float a0 = 0.f, a1 = 0.f, a2 = 0.f, a3 = 0.f;
    for (int e0 = beg; e0 < end; e0 += 32) {
#pragma unroll
        for (int j = 0; j < 8; ++j) {
            int e = e0 + 4 * j + grp;
            float m = (e < end) ? 1.f : 0.f;
            int ec = (e < end) ? e : (end - 1);
            int xu = (col[ec] >> 16) & 0x7F;
            float4 f = *((const float4*)(embW + (size_t)xu * D) + li);
            a0 += m * f.x; a1 += m * f.y; a2 += m * f.z; a3 += m * f.w;
        }
    }
    a0 += __shfl_xor(a0, 16); a0 += __shfl_xor(a0, 32);
    a1 += __shfl_xor(a1, 16); a1 += __shfl_xor(a1, 32);
    a2 += __shfl_xor(a2, 16); a2 += __shfl_xor(a2, 32);
    a3 += __shfl_xor(a3, 16); a3 += __shfl_xor(a3, 32);
    if (grp == 0) {
        float2 oh;
        *(__half2*)&oh.x = __floats2half2_rn(fmaxf(a0, 0.f), fmaxf(a1, 0.f));
        *(__half2*)&oh.y = __floats2half2_rn(fmaxf(a2, 0.f), fmaxf(a3, 0.f));
        ((float2*)(h1 + (size_t)v * D))[li] = oh;
    }
}

// ===== SAGE aggregate-first: s = mean_nb(h1) — float4 gathers =====

__global__ __launch_bounds__(256) void sage_s_agg_kernel(const int* __restrict__ rowbeg,
                                                         const int* __restrict__ rowend,
                                                         const int* __restrict__ col,
                                                         const __half* __restrict__ h1,
                                                         __half* __restrict__ s, int N) {
    int tid = threadIdx.x;
    int lane = tid & 63;
    int grp = lane >> 3, li = lane & 7;
    int v = blockIdx.x * 4 + (tid >> 6);
    if (v >= N) return;
    int beg = rowbeg[v], end = rowend[v];
    float a[8] = {0.f, 0.f, 0.f, 0.f, 0.f, 0.f, 0.f, 0.f};
    for (int e0 = beg; e0 < end; e0 += 32) {
#pragma unroll
        for (int j = 0; j < 4; ++j) {
            int e = e0 + 8 * j + grp;
            float m = (e < end) ? 1.f : 0.f;
            int ec = (e < end) ? e : (end - 1);
            int u = col[ec] & 0xFFFF;
            float4 r = *((const float4*)(h1 + (size_t)u * D) + li);
            const __half2* hp = (const __half2*)&r;
            float2 f0 = __half22float2(hp[0]);
            float2 f1 = __half22float2(hp[1]);
            float2 f2 = __half22float2(hp[2]);
            float2 f3 = __half22float2(hp[3]);
            a[0] += m * f0.x; a[1] += m * f0.y; a[2] += m * f1.x; a[3] += m * f1.y;
            a[4] += m * f2.x; a[5] += m * f2.y; a[6] += m * f3.x; a[7] += m * f3.y;
        }
    }
#pragma unroll
    for (int k = 0; k < 8; ++k) {
        a[k] += __shfl_xor(a[k], 8);
        a[k] += __shfl_xor(a[k], 16);
        a[k] += __shfl_xor(a[k], 32);
    }
    if (grp == 0) {
        float inv = 1.f / fmaxf((float)(end - beg), 1.f);
        float4 o;
        ((__half2*)&o)[0] = __floats2half2_rn(a[0] * inv, a[1] * inv);
        ((__half2*)&o)[1] = __floats2half2_rn(a[2] * inv, a[3] * inv);
        ((__half2*)&o)[2] = __floats2half2_rn(a[4] * inv, a[5] * inv);
        ((__half2*)&o)[3] = __floats2half2_rn(a[6] * inv, a[7] * inv);
        ((float4*)(s + (size_t)v * D))[li] = o;
    }
}

// ===== SAGE MLP: h2 = relu( s@Wsl + h1@Wsr ) — sequential two-tile staging =====

__global__ __launch_bounds__(256) void sage_mlp_kernel(
    const __half* __restrict__ s, const __half* __restrict__ h1, int nrows,
    const float* __restrict__ Wsl, const float* __restrict__ Wsr,
    __half* __restrict__ h2)
{
    __shared__ float At[64][68];     // 17.4 KB (s tile, then h1 tile in-place)
    __shared__ float Ws1[64][64];    // 16 KB
    __shared__ float Ws2[64][64];    // 16 KB
    int tid = threadIdx.x;
    {
        const float4* w1v = (const float4*)Wsl;
        const float4* w2v = (const float4*)Wsr;
        float4* s1 = (float4*)&Ws1[0][0];
        float4* s2 = (float4*)&Ws2[0][0];
        for (int i = tid; i < 1024; i += 256) { s1[i] = w1v[i]; s2[i] = w2v[i]; }
    }
    int r0 = blockIdx.x * 64;
    // stage s tile
    for (int i = tid; i < 512; i += 256) {
        int r = i >> 3, c8 = i & 7;
        int gr = r0 + r; if (gr >= nrows) gr = nrows - 1;
        float4 hv = ((const float4*)(s + (size_t)gr * D))[c8];
        const __half2* hp = (const __half2*)&hv;
        float* dp = &At[r][c8 * 8];
        float2 f;
        f = __half22float2(hp[0]); dp[0] = f.x; dp[1] = f.y;
        f = __half22float2(hp[1]); dp[2] = f.x; dp[3] = f.y;
        f = __half22float2(hp[2]); dp[4] = f.x; dp[5] = f.y;
        f = __half22float2(hp[3]); dp[6] = f.x; dp[7] = f.y;
    }
    __syncthreads();

    int cg = tid & 15;
    int rg = tid >> 4;

    // ---- GEMM 1: acc = s@Wsl ----
    float acc[4][4] = {{0.f}};
    for (int k0 = 0; k0 < 64; k0 += 4) {
        float4 a[4], w1[4];
#pragma unroll
        for (int i = 0; i < 4; ++i) a[i] = *(const float4*)&At[4 * rg + i][k0];
#pragma unroll
        for (int j = 0; j < 4; ++j) w1[j] = *(const float4*)&Ws1[k0 + j][cg * 4];
#pragma unroll
        for (int i = 0; i < 4; ++i) {
            float av[4] = {a[i].x, a[i].y, a[i].z, a[i].w};
#pragma unroll
            for (int kk = 0; kk < 4; ++kk) {
                acc[i][0] += av[kk] * w1[kk].x;
                acc[i][1] += av[kk] * w1[kk].y;
                acc[i][2] += av[kk] * w1[kk].z;
                acc[i][3] += av[kk] * w1[kk].w;
            }
        }
    }
    __syncthreads();   // all reads of s tile complete

    // stage h1 tile into same At
    for (int i = tid; i < 512; i += 256) {
        int r = i >> 3, c8 = i & 7;
        int gr = r0 + r; if (gr >= nrows) gr = nrows - 1;
        float4 hv = ((const float4*)(h1 + (size_t)gr * D))[c8];
        const __half2* hp = (const __half2*)&hv;
        float* dp = &At[r][c8 * 8];
        float2 f;
        f = __half22float2(hp[0]); dp[0] = f.x; dp[1] = f.y;
        f = __half22float2(hp[1]); dp[2] = f.x; dp[3] = f.y;
        f = __half22float2(hp[2]); dp[4] = f.x; dp[5] = f.y;
        f = __half22float2(hp[3]); dp[6] = f.x; dp[7] = f.y;
    }
    __syncthreads();

    // ---- GEMM 2: acc += h1@Wsr ----
    for (int k0 = 0; k0 < 64; k0 += 4) {
        float4 a[4], w2[4];
#pragma unroll
        for (int i = 0; i < 4; ++i) a[i] = *(const float4*)&At[4 * rg + i][k0];
#pragma unroll
        for (int j = 0; j < 4; ++j) w2[j] = *(const float4*)&Ws2[k0 + j][cg * 4];
#pragma unroll
        for (int i = 0; i < 4; ++i) {
            float av[4] = {a[i].x, a[i].y, a[i].z, a[i].w};
#pragma unroll
            for (int kk = 0; kk < 4; ++kk) {
                acc[i][0] += av[kk] * w2[kk].x;
                acc[i][1] += av[kk] * w2[kk].y;
                acc[i][2] += av[kk] * w2[kk].z;
                acc[i][3] += av[kk] * w2[kk].w;
            }
        }
    }
#pragma unroll
    for (int i = 0; i < 4; ++i) {
        int gr = r0 + 4 * rg + i;
        if (gr < nrows) {
            float2 oh;
            *(__half2*)&oh.x = __floats2half2_rn(fmaxf(acc[i][0], 0.f),
                                                 fmaxf(acc[i][1], 0.f));
            *(__half2*)&oh.y = __floats2half2_rn(fmaxf(acc[i][2], 0.f),
                                                 fmaxf(acc[i][3], 0.f));
            ((float2*)(h2 + (size_t)gr * D))[cg] = oh;
        }
    }
}

// ===== GIN aggregate-first: z = h2 + sum_nb(h2) — float4 gathers =====

__global__ __launch_bounds__(256) void gin_z_agg_kernel(const int* __restrict__ rowbeg,
                                                        const int* __restrict__ rowend,
                                                        const int* __restrict__ col,
                                                        const __half* __restrict__ h2,
                                                        __half* __restrict__ z, int N) {
    int tid = threadIdx.x;
    int lane = tid & 63;
    int grp = lane >> 3, li = lane & 7;
    int v = blockIdx.x * 4 + (tid >> 6);
    if (v >= N) return;
    int beg = rowbeg[v], end = rowend[v];
    float a[8] = {0.f, 0.f, 0.f, 0.f, 0.f, 0.f, 0.f, 0.f};
    for (int e0 = beg; e0 < end; e0 += 32) {
#pragma unroll
        for (int j = 0; j < 4; ++j) {
            int e = e0 + 8 * j + grp;
            float m = (e < end) ? 1.f : 0.f;
            int ec = (e < end) ? e : (end - 1);
            int u = col[ec] & 0xFFFF;
            float4 r = *((const float4*)(h2 + (size_t)u * D) + li);
            const __half2* hp = (const __half2*)&r;
            float2 f0 = __half22float2(hp[0]);
            float2 f1 = __half22float2(hp[1]);
            float2 f2 = __half22float2(hp[2]);
            float2 f3 = __half22float2(hp[3]);
            a[0] += m * f0.x; a[1] += m * f0.y; a[2] += m * f1.x; a[3] += m * f1.y;
            a[4] += m * f2.x; a[5] += m * f2.y; a[6] += m * f3.x; a[7] += m * f3.y;
        }
    }
#pragma unroll
    for (int k = 0; k < 8; ++k) {
        a[k] += __shfl_xor(a[k], 8);
        a[k] += __shfl_xor(a[k], 16);
        a[k] += __shfl_xor(a[k], 32);
    }
    if (grp == 0) {
        float4 rs = *((const float4*)(h2 + (size_t)v * D) + li);   // self term
        const __half2* sp = (const __half2*)&rs;
        float2 s0 = __half22float2(sp[0]);
        float2 s1 = __half22float2(sp[1]);
        float2 s2 = __half22float2(sp[2]);
        float2 s3 = __half22float2(sp[3]);
        float4 o;
        ((__half2*)&o)[0] = __floats2half2_rn(s0.x + a[0], s0.y + a[1]);
        ((__half2*)&o)[1] = __floats2half2_rn(s1.x + a[2], s1.y + a[3]);
        ((__half2*)&o)[2] = __floats2half2_rn(s2.x + a[4], s2.y + a[5]);
        ((__half2*)&o)[3] = __floats2half2_rn(s3.x + a[6], s3.y + a[7]);
        ((float4*)(z + (size_t)v * D))[li] = o;
    }
}

// ===== GIN MLP: h3 = relu( relu(z@Wg1+b1) @ Wg2 + b2 ) — two chained GEMMs =====

__global__ __launch_bounds__(256) void gin_mlp_kernel(
    const __half* __restrict__ z, int nrows,
    const float* __restrict__ Wg1, const float* __restrict__ b1,
    const float* __restrict__ Wg2, const float* __restrict__ b2,
    __half* __restrict__ h3)
{
    __shared__ float At[64][68];     // 17.4 KB (z tile, then t tile in-place)
    __shared__ float Ws1[64][64];    // 16 KB
    __shared__ float Ws2[64][64];    // 16 KB
    int tid = threadIdx.x;
    {
        const float4* w1v = (const float4*)Wg1;
        const float4* w2v = (const float4*)Wg2;
        float4* s1 = (float4*)&Ws1[0][0];
        float4* s2 = (float4*)&Ws2[0][0];
        for (int i = tid; i < 1024; i += 256) { s1[i] = w1v[i]; s2[i] = w2v[i]; }
    }
    int r0 = blockIdx.x * 64;
    for (int i = tid; i < 512; i += 256) {
        int r = i >> 3, c8 = i & 7;
        int gr = r0 + r; if (gr >= nrows) gr = nrows - 1;
        float4 hv = ((const float4*)(z + (size_t)gr * D))[c8];
        const __half2* hp = (const __half2*)&hv;
        float* dp = &At[r][c8 * 8];
        float2 f;
        f = __half22float2(hp[0]); dp[0] = f.x; dp[1] = f.y;
        f = __half22float2(hp[1]); dp[2] = f.x; dp[3] = f.y;
        f = __half22float2(hp[2]); dp[4] = f.x; dp[5] = f.y;
        f = __half22float2(hp[3]); dp[6] = f.x; dp[7] = f.y;
    }
    __syncthreads();

    int cg = tid & 15;
    int rg = tid >> 4;

    // ---- GEMM 1: t = relu(z@Wg1 + b1) ----
    float acc[4][4] = {{0.f}};
    for (int k0 = 0; k0 < 64; k0 += 4) {
        float4 a[4], w1[4];
#pragma unroll
        for (int i = 0; i < 4; ++i) a[i] = *(const float4*)&At[4 * rg + i][k0];
#pragma unroll
        for (int j = 0; j < 4; ++j) w1[j] = *(const float4*)&Ws1[k0 + j][cg * 4];
#pragma unroll
        for (int i = 0; i < 4; ++i) {
            float av[4] = {a[i].x, a[i].y, a[i].z, a[i].w};
#pragma unroll
            for (int kk = 0; kk < 4; ++kk) {
                acc[i][0] += av[kk] * w1[kk].x;
                acc[i][1] += av[kk] * w1[kk].y;
                acc[i][2] += av[kk] * w1[kk].z;
                acc[i][3] += av[kk] * w1[kk].w;
            }
        }
    }
    float4 bv1 = ((const float4*)b1)[cg];
    __syncthreads();   // all reads of At (z tile) complete
#pragma unroll
    for (int i = 0; i < 4; ++i) {
        float* dp = &At[4 * rg + i][cg * 4];
        dp[0] = fmaxf(acc[i][0] + bv1.x, 0.f);
        dp[1] = fmaxf(acc[i][1] + bv1.y, 0.f);
        dp[2] = fmaxf(acc[i][2] + bv1.z, 0.f);
        dp[3] = fmaxf(acc[i][3] + bv1.w, 0.f);
    }
    __syncthreads();   // t tile fully written

    // ---- GEMM 2: h3 = relu(t@Wg2 + b2) ----
    float acc2[4][4] = {{0.f}};
    for (int k0 = 0; k0 < 64; k0 += 4) {
        float4 a[4], w2[4];
#pragma unroll
        for (int i = 0; i < 4; ++i) a[i] = *(const float4*)&At[4 * rg + i][k0];
#pragma unroll
        for (int j = 0; j < 4; ++j) w2[j] = *(const float4*)&Ws2[k0 + j][cg * 4];
#pragma unroll
        for (int i = 0; i < 4; ++i) {
            float av[4] = {a[i].x, a[i].y, a[i].z, a[i].w};
#pragma unroll
            for (int kk = 0; kk < 4; ++kk) {
                acc2[i][0] += av[kk] * w2[kk].x;
                acc2[i][1] += av[kk] * w2[kk].y;
                acc2[i][2] += av[kk] * w2[kk].z;
                acc2[i][3] += av[kk] * w2[kk].w;
            }
        }
    }
    float4 bv2 = ((const float4*)b2)[cg];
#pragma unroll
    for (int i = 0; i < 4; ++i) {
        int gr = r0 + 4 * rg + i;
        if (gr < nrows) {
            float2 oh;
            *(__half2*)&oh.x = __floats2half2_rn(fmaxf(acc2[i][0] + bv2.x, 0.f),
                                                 fmaxf(acc2[i][1] + bv2.y, 0.f));
            *(__half2*)&oh.y = __floats2half2_rn(fmaxf(acc2[i][2] + bv2.z, 0.f),
                                                 fmaxf(acc2[i][3] + bv2.w, 0.f));
            ((float2*)(h3 + (size_t)gr * D))[cg] = oh;
        }
    }
}

// ===== pooling: 16 waves/graph, half2 reads, row-parity split + LDS tree reduce =====

__global__ __launch_bounds__(1024) void pool_final_kernel(
    const __half* __restrict__ h1, const __half* __restrict__ h2,
    const __half* __restrict__ h3,
    const int* __restrict__ batch, int N,
    const float* __restrict__ W1, const float* __restrict__ W2,
    const float* __restrict__ W3, float* __restrict__ out, int G) {
    __shared__ float r1[16][64];
    __shared__ float r2[16][64];
    __shared__ float r3[16][64];
    int g = blockIdx.x;
    int tid = threadIdx.x;
    int w = tid >> 6, lane = tid & 63;
    int half = lane >> 5, lc = lane & 31;   // lane covers cols 2lc,2lc+1 of row-parity `half`

    int lo = 0, hi = N;
    while (lo < hi) { int mid = (lo + hi) >> 1; if (batch[mid] < g) lo = mid + 1; else hi = mid; }
    int beg = lo;
    hi = N;
    while (lo < hi) { int mid = (lo + hi) >> 1; if (batch[mid] < g + 1) lo = mid + 1; else hi = mid; }
    int end = lo;

    float s1x = 0.f, s1y = 0.f, s2x = 0.f, s2y = 0.f, s3x = 0.f, s3y = 0.f;
    for (int v = beg + 2 * w + half; v < end; v += 32) {
        size_t ro = (size_t)v * D;
        float2 f1 = __half22float2(((const __half2*)(h1 + ro))[lc]);
        float2 f2 = __half22float2(((const __half2*)(h2 + ro))[lc]);
        float2 f3 = __half22float2(((const __half2*)(h3 + ro))[lc]);
        s1x += f1.x; s1y += f1.y;
        s2x += f2.x; s2y += f2.y;
        s3x += f3.x; s3y += f3.y;
    }
    // combine row parities (lane ^ 32 holds the other parity, same columns)
    s1x += __shfl_xor(s1x, 32); s1y += __shfl_xor(s1y, 32);
    s2x += __shfl_xor(s2x, 32); s2y += __shfl_xor(s2y, 32);
    s3x += __shfl_xor(s3x, 32); s3y += __shfl_xor(s3y, 32);
    if (half == 0) {
        ((float2*)r1[w])[lc] = make_float2(s1x, s1y);
        ((float2*)r2[w])[lc] = make_float2(s2x, s2y);
        ((float2*)r3[w])[lc] = make_float2(s3x, s3y);
    }
    __syncthreads();
#pragma unroll
    for (int stride = 8; stride >= 1; stride >>= 1) {
        if (w < stride) {
            r1[w][lane] += r1[w + stride][lane];
            r2[w][lane] += r2[w + stride][lane];
            r3[w][lane] += r3[w + stride][lane];
        }
        __syncthreads();
    }
    if (w == 0) {
        float inv = 1.f / fmaxf((float)(end - beg), 1.f);
        float p1 = r1[0][lane] * inv, p2 = r2[0][lane] * inv, p3 = r3[0][lane] * inv;
        float acc = 0.f;
#pragma unroll
        for (int k = 0; k < D; ++k) {
            acc += __shfl(p1, k) * W1[k * D + lane]
                 + __shfl(p2, k) * W2[k * D + lane]
                 + __shfl(p3, k) * W3[k * D + lane];
        }
        out[(size_t)g * D + lane] = fmaxf(acc, 0.f);
    }
}

// ================= launch =================

static inline size_t align256(size_t x) { return (x + 255) & ~(size_t)255; }

extern "C" void kernel_launch(void* const* d_in, const int* in_sizes, int n_in,
                              void* d_out, int out_size, void* d_ws, size_t ws_size,
                              hipStream_t stream) {
    const int* x      = (const int*)d_in[0];
    const int* ei     = (const int*)d_in[1];
    const int* batch  = (const int*)d_in[2];
    const float* emb  = (const float*)d_in[3];
    const float* Wgcn = (const float*)d_in[4];
    const float* Wsl  = (const float*)d_in[5];
    const float* Wsr  = (const float*)d_in[6];
    const float* Wg1  = (const float*)d_in[7];
    const float* bg1  = (const float*)d_in[8];
    const float* Wg2  = (const float*)d_in[9];
    const float* bg2  = (const float*)d_in[10];
    const float* Wp1  = (const float*)d_in[11];
    const float* Wp2  = (const float*)d_in[12];
    const float* Wp3  = (const float*)d_in[13];
    float* out = (float*)d_out;

    const int N = in_sizes[0];
    const int E = in_sizes[1] / 2;
    const int V = in_sizes[3] / D;
    const int G = out_size / D;
    const int* src = ei;
    const int* dst = ei + E;
    const int NBUCK = (N + 255) >> 8;

    // workspace layout
    char* base = (char*)d_ws;
    size_t off = 0;
    float* embW       = (float*)(base + off); off = align256(off + (size_t)V * D * 4);
    int* bucketFill   = (int*)(base + off);   off = align256(off + 256 * 4);
    int* rowbeg       = (int*)(base + off);   off = align256(off + (size_t)N * 4);
    int* rowend       = (int*)(base + off);   off = align256(off + (size_t)N * 4);
    int* ebuf         = (int*)(base + off);   off = align256(off + (size_t)NBUCK * ECAP * 4);
    int* col          = (int*)(base + off);   off = align256(off + (size_t)NBUCK * ECAP * 4);
    __half* h1        = (__half*)(base + off); off = align256(off + (size_t)N * D * 2);
    __half* h2        = (__half*)(base + off); off = align256(off + (size_t)N * D * 2);
    __half* h3        = (__half*)(base + off); off = align256(off + (size_t)N * D * 2);
    __half* sbuf      = (__half*)(base + off); off = align256(off + (size_t)N * D * 2);
    (void)ws_size;

    __half* z = sbuf;  // reuse: s dead after sage_mlp; z written by gin_z_agg

    hipMemsetAsync(bucketFill, 0, 256 * 4, stream);

    // fused: embW = emb @ Wgcn (blocks [0,NG)) + padded-bucket edge scatter (rest)
    const int NG = (V + 63) / 64;
    const int NTILE = (E + K3E - 1) / K3E;
    embw_scatter_kernel<<<NG + NTILE, 256, 0, stream>>>(emb, V, Wgcn, embW, NG,
                                                        src, dst, x, bucketFill, ebuf, E);

    // CSR build (per-bucket) then GCN gather at full occupancy -> h1 (fp16)
    csr_build_kernel<<<NBUCK, 1024, 0, stream>>>(ebuf, bucketFill, rowbeg, rowend, col, N);
    gcn_gather_kernel<<<(N + 3) / 4, 256, 0, stream>>>(rowbeg, rowend, col, embW, h1, N);

    // SAGE aggregate-first: s = mean_nb(h1), then h2 = relu(s@Wsl + h1@Wsr)
    int gb = (N + 63) / 64;
    sage_s_agg_kernel<<<(N + 3) / 4, 256, 0, stream>>>(rowbeg, rowend, col, h1, sbuf, N);
    sage_mlp_kernel<<<gb, 256, 0, stream>>>(sbuf, h1, N, Wsl, Wsr, h2);

    // GIN aggregate-first: z = h2 + sum_nb(h2), then fused 2-GEMM MLP -> h3
    gin_z_agg_kernel<<<(N + 3) / 4, 256, 0, stream>>>(rowbeg, rowend, col, h2, z, N);
    gin_mlp_kernel<<<gb, 256, 0, stream>>>(z, N, Wg1, bg1, Wg2, bg2, h3);

    // pooling (16 waves/graph, half2 reads, LDS reduce)
    pool_final_kernel<<<G, 1024, 0, stream>>>(h1, h2, h3, batch, N, Wp1, Wp2, Wp3, out, G);
}